// Round 7
// baseline (273.426 us; speedup 1.0000x reference)
//
#include <hip/hip_runtime.h>
#include <float.h>
#include <math.h>

typedef __attribute__((ext_vector_type(8))) short short8;
typedef __attribute__((ext_vector_type(4))) float f32x4;
typedef __attribute__((ext_vector_type(4))) unsigned short u16x4;
typedef unsigned short u16;
typedef unsigned int u32;

constexpr int B_ = 64, S_ = 512, N_ = 128, D_ = 768;

// ---------------------------------------------------------------------------
__device__ inline u16 bf16_rne(float x) {
    u32 u = __builtin_bit_cast(u32, x);
    u += 0x7FFFu + ((u >> 16) & 1u);
    return (u16)(u >> 16);
}
__device__ inline float bf2f(u16 h) {
    u32 u = ((u32)h) << 16;
    return __builtin_bit_cast(float, u);
}
__device__ inline void split2(float x, u16& h, u16& l) {
    h = bf16_rne(x);
    l = bf16_rne(x - bf2f(h));
}

__device__ inline void gload_lds16(const u16* g, u16* s) {
    __builtin_amdgcn_global_load_lds(
        (const __attribute__((address_space(1))) u32*)g,
        (__attribute__((address_space(3))) u32*)s, 16, 0, 0);
}

// ---------------------------------------------------------------------------
__global__ __launch_bounds__(192)
void span_split_kernel(const float* __restrict__ se, const int* __restrict__ spans,
                       u16* __restrict__ th, u16* __restrict__ tl) {
    const int bn = blockIdx.x;
    const int b  = bn >> 7;
    const int s  = spans[bn * 2 + 0];
    const int e  = spans[bn * 2 + 1];
    const float* base = se + (size_t)b * S_ * D_;
    const int d4 = threadIdx.x;
    float4 acc = make_float4(0.f, 0.f, 0.f, 0.f);
    for (int r = s + 1; r <= e; ++r) {
        const float4 v = reinterpret_cast<const float4*>(base + (size_t)r * D_)[d4];
        acc.x += v.x; acc.y += v.y; acc.z += v.z; acc.w += v.w;
    }
    u16x4 hv, lv;
    u16 hh, ll;
    split2(acc.x, hh, ll); hv[0] = hh; lv[0] = ll;
    split2(acc.y, hh, ll); hv[1] = hh; lv[1] = ll;
    split2(acc.z, hh, ll); hv[2] = hh; lv[2] = ll;
    split2(acc.w, hh, ll); hv[3] = hh; lv[3] = ll;
    *(u16x4*)(th + (size_t)bn * D_ + d4 * 4) = hv;
    *(u16x4*)(tl + (size_t)bn * D_ + d4 * 4) = lv;
}

// ---------------------------------------------------------------------------
__global__ __launch_bounds__(192)
void target_max_kernel(const float* __restrict__ se, const int* __restrict__ tspan,
                       float* __restrict__ tmax) {
    const int b = blockIdx.x;
    const int s = tspan[b * 2 + 0];
    const int e = tspan[b * 2 + 1];
    const float* base = se + (size_t)b * S_ * D_;
    const int d4 = threadIdx.x;
    float4 m = make_float4(-FLT_MAX, -FLT_MAX, -FLT_MAX, -FLT_MAX);
    for (int r = s; r < e; ++r) {
        const float4 v = reinterpret_cast<const float4*>(base + (size_t)r * D_)[d4];
        m.x = fmaxf(m.x, v.x); m.y = fmaxf(m.y, v.y);
        m.z = fmaxf(m.z, v.z); m.w = fmaxf(m.w, v.w);
    }
    reinterpret_cast<float4*>(tmax + (size_t)b * D_)[d4] = m;
}

// ---------------------------------------------------------------------------
// adj = clamp(dg+dg1,1) -> bf16 (exact {0,1}) [b][n][k]; invden = 1/(rowsum+1e-7)
__global__ __launch_bounds__(128)
void adj_kernel(const float* __restrict__ dg, const float* __restrict__ dg1,
                u16* __restrict__ adj, float* __restrict__ invden) {
    const int row = blockIdx.x;
    const int t   = threadIdx.x;
    const size_t idx = (size_t)row * N_ + t;
    float a = dg[idx] + dg1[idx];
    a = (a >= 1.f) ? 1.f : a;
    adj[idx] = bf16_rne(a);
    float w = a;
    #pragma unroll
    for (int off = 32; off; off >>= 1) w += __shfl_down(w, off, 64);
    __shared__ float ssum[2];
    if ((t & 63) == 0) ssum[t >> 6] = w;
    __syncthreads();
    if (t == 0) invden[row] = 1.f / (ssum[0] + ssum[1] + 1e-7f);
}

// ---------------------------------------------------------------------------
// Weights: W[k][n] (768x768) -> WT[n][k] split bf16 hi/lo. blockIdx.z = matrix.
__global__ __launch_bounds__(256)
void wsplit_kernel(const float* __restrict__ W0, const float* __restrict__ W1,
                   const float* __restrict__ W2, const float* __restrict__ W3,
                   u16* __restrict__ wth, u16* __restrict__ wtl) {
    __shared__ float t[64][65];
    const int mi = blockIdx.z;
    const float* W = (mi == 0) ? W0 : (mi == 1) ? W1 : (mi == 2) ? W2 : W3;
    const int k0 = blockIdx.y * 64, n0 = blockIdx.x * 64;
    #pragma unroll 4
    for (int it = 0; it < 16; ++it) {
        const int lin = it * 256 + threadIdx.x;
        const int r = lin >> 6, c = lin & 63;
        t[r][c] = W[(size_t)(k0 + r) * D_ + n0 + c];
    }
    __syncthreads();
    u16* oh = wth + (size_t)mi * D_ * D_;
    u16* ol = wtl + (size_t)mi * D_ * D_;
    #pragma unroll 4
    for (int it = 0; it < 16; ++it) {
        const int lin = it * 256 + threadIdx.x;
        const int r = lin >> 6, c = lin & 63;
        u16 h, l; split2(t[c][r], h, l);
        oh[(size_t)(n0 + r) * D_ + k0 + c] = h;
        ol[(size_t)(n0 + r) * D_ + k0 + c] = l;
    }
}

// ---------------------------------------------------------------------------
// Fused split-bf16 GEMM, 128x96 tile, 4 waves, 512 blocks (2/CU).
// A-fragments: direct global->VGPR (asm dwordx4), double-buffered 1 K-step
// ahead. B: LDS double buffer (2 x 12 KB), hi/lo interleaved 8-chunk rows,
// chunk p = q ^ (row&7) pre-applied on the global source. adj: dedicated
// LDS [12288,28672), staged at t==22. hwT reuses B buffers after the loop.
// MODE 0: store relu(H) split hi/lo row-major.
// MODE 1: phase 2: out = relu((adj[b]@H)*invden + bias) + X_in.
template<int MODE>
__global__ __launch_bounds__(256, 2)
void gemm_fused(const u16* __restrict__ Ah, const u16* __restrict__ Al,
                const u16* __restrict__ Bh, const u16* __restrict__ Bl,
                const u16* __restrict__ ADJ, const float* __restrict__ invden,
                const float* __restrict__ bias,
                u16* __restrict__ Oh, u16* __restrict__ Ol) {
    __shared__ u16 lds[28672];   // 56 KB: B buf0 | B buf1 | adj(16384 u16)
    const int tid  = threadIdx.x;
    const int lane = tid & 63, w = tid >> 6;
    const int wr = w >> 1, wc = w & 1;
    const int lr = lane & 15, lh = lane >> 4;

    int bid = blockIdx.x;
    bid = (bid & 7) * 64 + (bid >> 3);      // XCD swizzle, 512 % 8 == 0
    const int bnb = bid & 7, bmb = bid >> 3;
    const int bm = bmb * 128, bn = bnb * 96;

    // --- B staging: 12 groups (8 rows x 8 chunks of 16B), 3 per wave ---
    const int lr3 = lane >> 3;
    const int q   = (lane & 7) ^ lr3;
    const int qk  = (q & 3) * 8;
    const u16* bBase = (q & 4) ? Bl : Bh;
    const u16* gB[3];
    #pragma unroll
    for (int i = 0; i < 3; ++i)
        gB[i] = bBase + (size_t)(bn + (w * 3 + i) * 8 + lr3) * 768 + qk;

    // --- A direct-to-register bases (frag layout: row=..+lr, k0=lh*8) ---
    const u16* gAh = Ah + (size_t)(bm + wr * 64 + lr) * 768 + lh * 8;
    const u16* gAl = Al + (size_t)(bm + wr * 64 + lr) * 768 + lh * 8;

    // adj staging lane constants (MODE 1)
    const int anl = lane >> 4;
    const int ap  = lane & 15;

    f32x4 acc[4][3];
    #pragma unroll
    for (int i = 0; i < 4; ++i)
        #pragma unroll
        for (int j = 0; j < 3; ++j)
            acc[i][j] = (f32x4){0.f, 0.f, 0.f, 0.f};

    short8 aA[8], aB[8];   // [0..3] hi frags, [4..7] lo frags

    // prologue: tile 0
    #pragma unroll
    for (int i = 0; i < 3; ++i)
        gload_lds16(gB[i], lds + (w * 3 + i) * 512);
    #pragma unroll
    for (int mf = 0; mf < 4; ++mf) {
        asm volatile("global_load_dwordx4 %0, %1, off"
                     : "=v"(aA[mf]) : "v"(gAh + (size_t)mf * 12288) : "memory");
        asm volatile("global_load_dwordx4 %0, %1, off"
                     : "=v"(aA[4 + mf]) : "v"(gAl + (size_t)mf * 12288) : "memory");
    }

    const int r7  = lr & 7;
    const int pHi = (lh ^ r7) << 3;
    const int pLo = ((4 | lh) ^ r7) << 3;

#define GEMM_ITER(T, CUR, NXT)                                                \
    {                                                                         \
        const int t_ = (T);                                                   \
        if (t_ < 23) {                                                        \
            u16* bbuf = lds + ((t_ + 1) & 1) * 6144;                          \
            _Pragma("unroll")                                                 \
            for (int i = 0; i < 3; ++i)                                       \
                gload_lds16(gB[i] + (t_ + 1) * 32, bbuf + (w * 3 + i) * 512); \
            _Pragma("unroll")                                                 \
            for (int mf = 0; mf < 4; ++mf) {                                  \
                asm volatile("global_load_dwordx4 %0, %1, off"                \
                    : "=v"(NXT[mf])                                           \
                    : "v"(gAh + (size_t)mf * 12288 + (t_ + 1) * 32)           \
                    : "memory");                                              \
                asm volatile("global_load_dwordx4 %0, %1, off"                \
                    : "=v"(NXT[4 + mf])                                       \
                    : "v"(gAl + (size_t)mf * 12288 + (t_ + 1) * 32)           \
                    : "memory");                                              \
            }                                                                 \
            asm volatile("s_waitcnt vmcnt(11)" ::: "memory");                 \
        } else {                                                              \
            asm volatile("s_waitcnt vmcnt(0)" ::: "memory");                  \
        }                                                                     \
        __builtin_amdgcn_s_barrier();                                         \
        __builtin_amdgcn_sched_barrier(0);                                    \
        if (MODE == 1 && t_ == 22) {                                          \
            const u16* adjb = ADJ + (size_t)bmb * (N_ * N_);                  \
            _Pragma("unroll")                                                 \
            for (int i = 0; i < 8; ++i) {                                     \
                const int j = w * 8 + i;                                      \
                const int node = j * 4 + anl;                                 \
                gload_lds16(adjb + (size_t)node * 128 + ((ap ^ (node & 7)) << 3), \
                            lds + 12288 + j * 512);                           \
            }                                                                 \
        }                                                                     \
        const u16* Lb = lds + (t_ & 1) * 6144;                                \
        short8 bh4[3], bl4[3];                                                \
        _Pragma("unroll")                                                     \
        for (int f = 0; f < 3; ++f) {                                         \
            const int rb = (wc * 48 + f * 16 + lr) * 64;                      \
            bh4[f] = *(const short8*)&Lb[rb + pHi];                           \
            bl4[f] = *(const short8*)&Lb[rb + pLo];                           \
        }                                                                     \
        __builtin_amdgcn_s_setprio(1);                                        \
        _Pragma("unroll")                                                     \
        for (int mf = 0; mf < 4; ++mf)                                        \
            _Pragma("unroll")                                                 \
            for (int nf = 0; nf < 3; ++nf) {                                  \
                acc[mf][nf] = __builtin_amdgcn_mfma_f32_16x16x32_bf16(CUR[mf], bh4[nf], acc[mf][nf], 0, 0, 0);      \
                acc[mf][nf] = __builtin_amdgcn_mfma_f32_16x16x32_bf16(CUR[mf], bl4[nf], acc[mf][nf], 0, 0, 0);      \
                acc[mf][nf] = __builtin_amdgcn_mfma_f32_16x16x32_bf16(CUR[4 + mf], bh4[nf], acc[mf][nf], 0, 0, 0);  \
            }                                                                 \
        __builtin_amdgcn_s_setprio(0);                                        \
        asm volatile("s_waitcnt lgkmcnt(0)" ::: "memory");                    \
        __builtin_amdgcn_s_barrier();                                         \
    }

    for (int tt = 0; tt < 12; ++tt) {
        GEMM_ITER(2 * tt,     aA, aB)
        GEMM_ITER(2 * tt + 1, aB, aA)
    }
#undef GEMM_ITER

    if (MODE == 0) {
        #pragma unroll
        for (int mf = 0; mf < 4; ++mf)
            #pragma unroll
            for (int r = 0; r < 4; ++r) {
                const int row = bm + wr * 64 + mf * 16 + lh * 4 + r;
                #pragma unroll
                for (int nf = 0; nf < 3; ++nf) {
                    const int c = bn + wc * 48 + nf * 16 + lr;
                    const float v = fmaxf(acc[mf][nf][r], 0.f);
                    u16 h, l; split2(v, h, l);
                    const size_t gi = (size_t)row * 768 + c;
                    Oh[gi] = h; Ol[gi] = l;
                }
            }
        return;
    }

    // ---------------- MODE 1: phase 2 (adjacency GEMM in-LDS) ----------------
    const u16* adjL = lds + 12288;   // adj [128 node][16 chunks swizzled]
    u16* hwT = lds;                  // H^T [96 c][128 node] swizzled (B bufs dead)

    // write HI halves of H^T; keep LO in registers
    u16x4 lv[4][3];
    #pragma unroll
    for (int mf = 0; mf < 4; ++mf) {
        const int node0 = wr * 64 + mf * 16 + lh * 4;
        #pragma unroll
        for (int nf = 0; nf < 3; ++nf) {
            const int c = wc * 48 + nf * 16 + lr;
            u16x4 hv;
            #pragma unroll
            for (int r = 0; r < 4; ++r) {
                u16 h, l; split2(acc[mf][nf][r], h, l);
                hv[r] = h; lv[mf][nf][r] = l;
            }
            *(u16x4*)&hwT[c * 128 + (((node0 >> 3) ^ (c & 7)) << 3) + (node0 & 7)] = hv;
        }
    }
    asm volatile("s_waitcnt lgkmcnt(0)" ::: "memory");
    __builtin_amdgcn_s_barrier();
    __builtin_amdgcn_sched_barrier(0);

    f32x4 acc2[4][3];
    #pragma unroll
    for (int i = 0; i < 4; ++i)
        #pragma unroll
        for (int j = 0; j < 3; ++j)
            acc2[i][j] = (f32x4){0.f, 0.f, 0.f, 0.f};

    #pragma unroll
    for (int pass = 0; pass < 2; ++pass) {
        if (pass == 1) {
            #pragma unroll
            for (int mf = 0; mf < 4; ++mf) {
                const int node0 = wr * 64 + mf * 16 + lh * 4;
                #pragma unroll
                for (int nf = 0; nf < 3; ++nf) {
                    const int c = wc * 48 + nf * 16 + lr;
                    *(u16x4*)&hwT[c * 128 + (((node0 >> 3) ^ (c & 7)) << 3) + (node0 & 7)] = lv[mf][nf];
                }
            }
            asm volatile("s_waitcnt lgkmcnt(0)" ::: "memory");
            __builtin_amdgcn_s_barrier();
            __builtin_amdgcn_sched_barrier(0);
        }
        #pragma unroll
        for (int ks = 0; ks < 4; ++ks) {
            short8 af[4], bf[3];
            #pragma unroll
            for (int f = 0; f < 4; ++f) {
                const int node = wr * 64 + f * 16 + lr;
                af[f] = *(const short8*)&adjL[node * 128 + (((ks * 4 + lh) ^ (node & 7)) << 3)];
            }
            #pragma unroll
            for (int f = 0; f < 3; ++f) {
                const int c = wc * 48 + f * 16 + lr;
                bf[f] = *(const short8*)&hwT[c * 128 + (((ks * 4 + lh) ^ (c & 7)) << 3)];
            }
            #pragma unroll
            for (int mf = 0; mf < 4; ++mf)
                #pragma unroll
                for (int nf = 0; nf < 3; ++nf)
                    acc2[mf][nf] = __builtin_amdgcn_mfma_f32_16x16x32_bf16(af[mf], bf[nf], acc2[mf][nf], 0, 0, 0);
        }
        if (pass == 0) {
            asm volatile("s_waitcnt lgkmcnt(0)" ::: "memory");
            __builtin_amdgcn_s_barrier();
            __builtin_amdgcn_sched_barrier(0);
        }
    }

    // epilogue: out = relu(acc2*inv + bias) + X_in; split; store
    #pragma unroll
    for (int mf = 0; mf < 4; ++mf)
        #pragma unroll
        for (int r = 0; r < 4; ++r) {
            const int node = wr * 64 + mf * 16 + lh * 4 + r;
            const float inv = invden[bmb * N_ + node];
            const size_t rowbase = (size_t)(bmb * N_ + node) * 768 + bn;
            #pragma unroll
            for (int nf = 0; nf < 3; ++nf) {
                const int c = wc * 48 + nf * 16 + lr;
                float v = fmaxf(acc2[mf][nf][r] * inv + bias[bn + c], 0.f);
                const size_t gi = rowbase + c;
                v += bf2f(Ah[gi]) + bf2f(Al[gi]);   // residual = A-source
                u16 h, l; split2(v, h, l);
                Oh[gi] = h; Ol[gi] = l;
            }
        }
}

// ---------------------------------------------------------------------------
__global__ __launch_bounds__(192)
void gcn_target_kernel(const u16* __restrict__ Xh, const u16* __restrict__ Xl,
                       const int* __restrict__ gspan, float* __restrict__ gt) {
    const int b = blockIdx.x;
    const int s = gspan[b * 2 + 0];
    const int e = gspan[b * 2 + 1];
    const int d4 = threadIdx.x;
    float4 acc = make_float4(0.f, 0.f, 0.f, 0.f);
    for (int n = s; n < e; ++n) {
        const size_t base = (size_t)(b * N_ + n) * D_ + d4 * 4;
        const u16x4 h = *(const u16x4*)(Xh + base);
        const u16x4 l = *(const u16x4*)(Xl + base);
        acc.x += bf2f(h[0]) + bf2f(l[0]);
        acc.y += bf2f(h[1]) + bf2f(l[1]);
        acc.z += bf2f(h[2]) + bf2f(l[2]);
        acc.w += bf2f(h[3]) + bf2f(l[3]);
    }
    reinterpret_cast<float4*>(gt + (size_t)b * D_)[d4] = acc;
}

// ---------------------------------------------------------------------------
__global__ __launch_bounds__(256)
void head_kernel(const float* __restrict__ tmax, const float* __restrict__ gt,
                 const float* __restrict__ fcW, const float* __restrict__ fcb,
                 float* __restrict__ out) {
    const int b = blockIdx.x;
    const int t = threadIdx.x;
    float p0 = 0.f, p1 = 0.f, p2 = 0.f;
    for (int i = t; i < 2 * D_; i += 256) {
        const float v = (i < D_) ? tmax[(size_t)b * D_ + i] : gt[(size_t)b * D_ + i - D_];
        p0 += v * fcW[i * 3 + 0];
        p1 += v * fcW[i * 3 + 1];
        p2 += v * fcW[i * 3 + 2];
    }
    #pragma unroll
    for (int off = 32; off; off >>= 1) {
        p0 += __shfl_down(p0, off, 64);
        p1 += __shfl_down(p1, off, 64);
        p2 += __shfl_down(p2, off, 64);
    }
    __shared__ float red[4][3];
    const int wv = t >> 6;
    if ((t & 63) == 0) { red[wv][0] = p0; red[wv][1] = p1; red[wv][2] = p2; }
    __syncthreads();
    if (t == 0) {
        #pragma unroll
        for (int o = 0; o < 3; ++o) {
            const float s = red[0][o] + red[1][o] + red[2][o] + red[3][o] + fcb[o];
            out[b * 3 + o] = tanhf(s);
        }
    }
}

// ---------------------------------------------------------------------------
extern "C" void kernel_launch(void* const* d_in, const int* in_sizes, int n_in,
                              void* d_out, int out_size, void* d_ws, size_t ws_size,
                              hipStream_t stream) {
    const float* se   = (const float*)d_in[0];
    const float* dg   = (const float*)d_in[1];
    const float* dg1  = (const float*)d_in[2];
    const float* Wp   = (const float*)d_in[3];
    const float* Wg[3] = {(const float*)d_in[4], (const float*)d_in[6], (const float*)d_in[8]};
    const float* bg[3] = {(const float*)d_in[5], (const float*)d_in[7], (const float*)d_in[9]};
    const float* fcW  = (const float*)d_in[10];
    const float* fcb  = (const float*)d_in[11];
    const int*   tspan  = (const int*)d_in[12];
    const int*   nspans = (const int*)d_in[13];
    const int*   gspan  = (const int*)d_in[14];
    float* out = (float*)d_out;

    // workspace layout (u16 units unless noted)
    u16* us   = (u16*)d_ws;
    u16* X0h  = us;                        // 8192*768 each
    u16* X0l  = X0h + 6291456;
    u16* X1h  = X0l + 6291456;
    u16* X1l  = X1h + 6291456;
    u16* TH   = X1l + 6291456;             // tmps hi/lo
    u16* TL   = TH  + 6291456;
    u16* WTh  = TL  + 6291456;             // 4*768*768
    u16* WTl  = WTh + 2359296;
    u16* ADJ  = WTl + 2359296;             // 64*128*128
    float* INV = (float*)(ADJ + 1048576);  // 8192
    float* TMX = INV + 8192;               // 64*768
    float* GT  = TMX + 49152;              // 64*768

    // Stage A: ragged prep
    span_split_kernel<<<B_ * N_, 192, 0, stream>>>(se, nspans, TH, TL);
    target_max_kernel<<<B_, 192, 0, stream>>>(se, tspan, TMX);
    adj_kernel<<<B_ * N_, 128, 0, stream>>>(dg, dg1, ADJ, INV);
    wsplit_kernel<<<dim3(12, 12, 4), 256, 0, stream>>>(Wp, Wg[0], Wg[1], Wg[2], WTh, WTl);

    // Stage B: X0 = relu(tmps @ W_proj)   (512 blocks: 64 row-panels x 8 col-96)
    gemm_fused<0><<<512, 256, 0, stream>>>(TH, TL, WTh, WTl,
                                           nullptr, nullptr, nullptr, X0h, X0l);

    // Stage C: 3 fused GCN layers (ping-pong X0 <-> X1)
    const u16* inh[3] = {X0h, X1h, X0h};
    const u16* inl[3] = {X0l, X1l, X0l};
    u16* outh[3] = {X1h, X0h, X1h};
    u16* outl[3] = {X1l, X0l, X1l};
    for (int l = 0; l < 3; ++l) {
        const size_t wo = (size_t)(l + 1) * D_ * D_;
        gemm_fused<1><<<512, 256, 0, stream>>>(inh[l], inl[l], WTh + wo, WTl + wo,
                                               ADJ, INV, bg[l], outh[l], outl[l]);
    }

    // Stage D: ragged node-span sum + head (final X lives in X1)
    gcn_target_kernel<<<B_, 192, 0, stream>>>(X1h, X1l, gspan, GT);
    head_kernel<<<B_, 256, 0, stream>>>(TMX, GT, fcW, fcb, out);
}

// Round 8
// 195.456 us; speedup vs baseline: 1.3989x; 1.3989x over previous
//
#include <hip/hip_runtime.h>
#include <float.h>
#include <math.h>

typedef __attribute__((ext_vector_type(8))) short short8;
typedef __attribute__((ext_vector_type(4))) float f32x4;
typedef __attribute__((ext_vector_type(4))) unsigned short u16x4;
typedef unsigned short u16;
typedef unsigned int u32;

constexpr int B_ = 64, S_ = 512, N_ = 128, D_ = 768;

// ---------------------------------------------------------------------------
__device__ inline u16 bf16_rne(float x) {
    u32 u = __builtin_bit_cast(u32, x);
    u += 0x7FFFu + ((u >> 16) & 1u);
    return (u16)(u >> 16);
}
__device__ inline float bf2f(u16 h) {
    u32 u = ((u32)h) << 16;
    return __builtin_bit_cast(float, u);
}
__device__ inline void split2(float x, u16& h, u16& l) {
    h = bf16_rne(x);
    l = bf16_rne(x - bf2f(h));
}

__device__ inline void gload_lds16(const u16* g, u16* s) {
    __builtin_amdgcn_global_load_lds(
        (const __attribute__((address_space(1))) u32*)g,
        (__attribute__((address_space(3))) u32*)s, 16, 0, 0);
}

// Fragment-major layout for activation matrices [M][768]:
// u16 index of element (row, col) = ((row>>4)*24 + (col>>5))*512
//                                 + ((col>>3)&3)*128 + (row&15)*8 + (col&7)
__device__ inline int fragIdx(int row, int col) {
    return ((row >> 4) * 24 + (col >> 5)) * 512 + ((col >> 3) & 3) * 128
         + (row & 15) * 8 + (col & 7);
}

// ---------------------------------------------------------------------------
// tmps[b,n,:] = sum_{r=s+1..e} se[b,r,:]  -> split bf16 hi/lo, FRAG layout
__global__ __launch_bounds__(192)
void span_split_kernel(const float* __restrict__ se, const int* __restrict__ spans,
                       u16* __restrict__ th, u16* __restrict__ tl) {
    const int bn = blockIdx.x;
    const int b  = bn >> 7;
    const int s  = spans[bn * 2 + 0];
    const int e  = spans[bn * 2 + 1];
    const float* base = se + (size_t)b * S_ * D_;
    const int d4 = threadIdx.x;
    float4 acc = make_float4(0.f, 0.f, 0.f, 0.f);
    for (int r = s + 1; r <= e; ++r) {
        const float4 v = reinterpret_cast<const float4*>(base + (size_t)r * D_)[d4];
        acc.x += v.x; acc.y += v.y; acc.z += v.z; acc.w += v.w;
    }
    u16x4 hv, lv;
    u16 hh, ll;
    split2(acc.x, hh, ll); hv[0] = hh; lv[0] = ll;
    split2(acc.y, hh, ll); hv[1] = hh; lv[1] = ll;
    split2(acc.z, hh, ll); hv[2] = hh; lv[2] = ll;
    split2(acc.w, hh, ll); hv[3] = hh; lv[3] = ll;
    const int idx = fragIdx(bn, d4 * 4);
    *(u16x4*)(th + idx) = hv;
    *(u16x4*)(tl + idx) = lv;
}

// ---------------------------------------------------------------------------
__global__ __launch_bounds__(192)
void target_max_kernel(const float* __restrict__ se, const int* __restrict__ tspan,
                       float* __restrict__ tmax) {
    const int b = blockIdx.x;
    const int s = tspan[b * 2 + 0];
    const int e = tspan[b * 2 + 1];
    const float* base = se + (size_t)b * S_ * D_;
    const int d4 = threadIdx.x;
    float4 m = make_float4(-FLT_MAX, -FLT_MAX, -FLT_MAX, -FLT_MAX);
    for (int r = s; r < e; ++r) {
        const float4 v = reinterpret_cast<const float4*>(base + (size_t)r * D_)[d4];
        m.x = fmaxf(m.x, v.x); m.y = fmaxf(m.y, v.y);
        m.z = fmaxf(m.z, v.z); m.w = fmaxf(m.w, v.w);
    }
    reinterpret_cast<float4*>(tmax + (size_t)b * D_)[d4] = m;
}

// ---------------------------------------------------------------------------
// adj = clamp(dg+dg1,1) -> bf16 (exact {0,1}) [b][n][k]; invden = 1/(rowsum+1e-7)
__global__ __launch_bounds__(128)
void adj_kernel(const float* __restrict__ dg, const float* __restrict__ dg1,
                u16* __restrict__ adj, float* __restrict__ invden) {
    const int row = blockIdx.x;
    const int t   = threadIdx.x;
    const size_t idx = (size_t)row * N_ + t;
    float a = dg[idx] + dg1[idx];
    a = (a >= 1.f) ? 1.f : a;
    adj[idx] = bf16_rne(a);
    float w = a;
    #pragma unroll
    for (int off = 32; off; off >>= 1) w += __shfl_down(w, off, 64);
    __shared__ float ssum[2];
    if ((t & 63) == 0) ssum[t >> 6] = w;
    __syncthreads();
    if (t == 0) invden[row] = 1.f / (ssum[0] + ssum[1] + 1e-7f);
}

// ---------------------------------------------------------------------------
// Weights: W[k][n] (768x768) -> WT[n][k] split bf16 hi/lo. blockIdx.z = matrix.
__global__ __launch_bounds__(256)
void wsplit_kernel(const float* __restrict__ W0, const float* __restrict__ W1,
                   const float* __restrict__ W2, const float* __restrict__ W3,
                   u16* __restrict__ wth, u16* __restrict__ wtl) {
    __shared__ float t[64][65];
    const int mi = blockIdx.z;
    const float* W = (mi == 0) ? W0 : (mi == 1) ? W1 : (mi == 2) ? W2 : W3;
    const int k0 = blockIdx.y * 64, n0 = blockIdx.x * 64;
    #pragma unroll 4
    for (int it = 0; it < 16; ++it) {
        const int lin = it * 256 + threadIdx.x;
        const int r = lin >> 6, c = lin & 63;
        t[r][c] = W[(size_t)(k0 + r) * D_ + n0 + c];
    }
    __syncthreads();
    u16* oh = wth + (size_t)mi * D_ * D_;
    u16* ol = wtl + (size_t)mi * D_ * D_;
    #pragma unroll 4
    for (int it = 0; it < 16; ++it) {
        const int lin = it * 256 + threadIdx.x;
        const int r = lin >> 6, c = lin & 63;
        u16 h, l; split2(t[c][r], h, l);
        oh[(size_t)(n0 + r) * D_ + k0 + c] = h;
        ol[(size_t)(n0 + r) * D_ + k0 + c] = l;
    }
}

// ---------------------------------------------------------------------------
// Fused split-bf16 GEMM, 128x96 tile, 4 waves, 512 blocks (2/CU).
// A (activations): FRAG-layout global -> VGPR, coalesced (base+lane*16B),
// double-buffered 1 K-step ahead via inline-asm dwordx4 (counted vmcnt).
// B (weights): LDS double buffer (2 x 12 KB), hi/lo interleaved 8-chunk rows,
// chunk p = q ^ (row&7) pre-applied on the global source. adj: dedicated
// LDS [12288,28672), staged at t==22. hwT reuses B buffers after the loop.
// MODE 0: store relu(H) split hi/lo in FRAG layout.
// MODE 1: phase 2: out = relu((adj[b]@H)*invden + bias) + X_in (FRAG layout).
template<int MODE>
__global__ __launch_bounds__(256, 2)
void gemm_fused(const u16* __restrict__ Ah, const u16* __restrict__ Al,
                const u16* __restrict__ Bh, const u16* __restrict__ Bl,
                const u16* __restrict__ ADJ, const float* __restrict__ invden,
                const float* __restrict__ bias,
                u16* __restrict__ Oh, u16* __restrict__ Ol) {
    __shared__ u16 lds[28672];   // 56 KB: B buf0 | B buf1 | adj(16384 u16)
    const int tid  = threadIdx.x;
    const int lane = tid & 63, w = tid >> 6;
    const int wr = w >> 1, wc = w & 1;
    const int lr = lane & 15, lh = lane >> 4;

    int bid = blockIdx.x;
    bid = (bid & 7) * 64 + (bid >> 3);      // XCD swizzle, 512 % 8 == 0
    const int bnb = bid & 7, bmb = bid >> 3;
    const int bn = bnb * 96;

    // --- B staging: 12 groups (8 rows x 8 chunks of 16B), 3 per wave ---
    const int lr3 = lane >> 3;
    const int q   = (lane & 7) ^ lr3;
    const int qk  = (q & 3) * 8;
    const u16* bBase = (q & 4) ? Bl : Bh;
    const u16* gB[3];
    #pragma unroll
    for (int i = 0; i < 3; ++i)
        gB[i] = bBase + (size_t)(bn + (w * 3 + i) * 8 + lr3) * 768 + qk;

    // --- A frag-layout bases: tile (mblk, t) at (mblk*24 + t)*512 + lane*8 ---
    const int mblk0 = bmb * 8 + wr * 4;
    const u16* gAh = Ah + (size_t)mblk0 * 24 * 512 + lane * 8;
    const u16* gAl = Al + (size_t)mblk0 * 24 * 512 + lane * 8;

    // adj staging lane constants (MODE 1)
    const int anl = lane >> 4;
    const int ap  = lane & 15;

    f32x4 acc[4][3];
    #pragma unroll
    for (int i = 0; i < 4; ++i)
        #pragma unroll
        for (int j = 0; j < 3; ++j)
            acc[i][j] = (f32x4){0.f, 0.f, 0.f, 0.f};

    short8 aA[8], aB[8];   // [0..3] hi frags, [4..7] lo frags

    // prologue: tile 0
    #pragma unroll
    for (int i = 0; i < 3; ++i)
        gload_lds16(gB[i], lds + (w * 3 + i) * 512);
    #pragma unroll
    for (int mf = 0; mf < 4; ++mf) {
        asm volatile("global_load_dwordx4 %0, %1, off"
                     : "=v"(aA[mf]) : "v"(gAh + mf * 12288) : "memory");
        asm volatile("global_load_dwordx4 %0, %1, off"
                     : "=v"(aA[4 + mf]) : "v"(gAl + mf * 12288) : "memory");
    }

    const int r7  = lr & 7;
    const int pHi = (lh ^ r7) << 3;
    const int pLo = ((4 | lh) ^ r7) << 3;

#define GEMM_ITER(T, CUR, NXT)                                                \
    {                                                                         \
        const int t_ = (T);                                                   \
        if (t_ < 23) {                                                        \
            u16* bbuf = lds + ((t_ + 1) & 1) * 6144;                          \
            _Pragma("unroll")                                                 \
            for (int i = 0; i < 3; ++i)                                       \
                gload_lds16(gB[i] + (t_ + 1) * 32, bbuf + (w * 3 + i) * 512); \
            _Pragma("unroll")                                                 \
            for (int mf = 0; mf < 4; ++mf) {                                  \
                asm volatile("global_load_dwordx4 %0, %1, off"                \
                    : "=v"(NXT[mf])                                           \
                    : "v"(gAh + mf * 12288 + (t_ + 1) * 512) : "memory");     \
                asm volatile("global_load_dwordx4 %0, %1, off"                \
                    : "=v"(NXT[4 + mf])                                       \
                    : "v"(gAl + mf * 12288 + (t_ + 1) * 512) : "memory");     \
            }                                                                 \
            asm volatile("s_waitcnt vmcnt(11)" ::: "memory");                 \
        } else {                                                              \
            asm volatile("s_waitcnt vmcnt(0)" ::: "memory");                  \
        }                                                                     \
        __builtin_amdgcn_s_barrier();                                         \
        __builtin_amdgcn_sched_barrier(0);                                    \
        if (MODE == 1 && t_ == 22) {                                          \
            const u16* adjb = ADJ + (size_t)bmb * (N_ * N_);                  \
            _Pragma("unroll")                                                 \
            for (int i = 0; i < 8; ++i) {                                     \
                const int j = w * 8 + i;                                      \
                const int node = j * 4 + anl;                                 \
                gload_lds16(adjb + (size_t)node * 128 + ((ap ^ (node & 7)) << 3), \
                            lds + 12288 + j * 512);                           \
            }                                                                 \
        }                                                                     \
        const u16* Lb = lds + (t_ & 1) * 6144;                                \
        short8 bh4[3], bl4[3];                                                \
        _Pragma("unroll")                                                     \
        for (int f = 0; f < 3; ++f) {                                         \
            const int rb = (wc * 48 + f * 16 + lr) * 64;                      \
            bh4[f] = *(const short8*)&Lb[rb + pHi];                           \
            bl4[f] = *(const short8*)&Lb[rb + pLo];                           \
        }                                                                     \
        __builtin_amdgcn_s_setprio(1);                                        \
        _Pragma("unroll")                                                     \
        for (int mf = 0; mf < 4; ++mf)                                        \
            _Pragma("unroll")                                                 \
            for (int nf = 0; nf < 3; ++nf) {                                  \
                acc[mf][nf] = __builtin_amdgcn_mfma_f32_16x16x32_bf16(CUR[mf], bh4[nf], acc[mf][nf], 0, 0, 0);      \
                acc[mf][nf] = __builtin_amdgcn_mfma_f32_16x16x32_bf16(CUR[mf], bl4[nf], acc[mf][nf], 0, 0, 0);      \
                acc[mf][nf] = __builtin_amdgcn_mfma_f32_16x16x32_bf16(CUR[4 + mf], bh4[nf], acc[mf][nf], 0, 0, 0);  \
            }                                                                 \
        __builtin_amdgcn_s_setprio(0);                                        \
        asm volatile("s_waitcnt lgkmcnt(0)" ::: "memory");                    \
        __builtin_amdgcn_s_barrier();                                         \
    }

    for (int tt = 0; tt < 12; ++tt) {
        GEMM_ITER(2 * tt,     aA, aB)
        GEMM_ITER(2 * tt + 1, aB, aA)
    }
#undef GEMM_ITER

    if (MODE == 0) {
        #pragma unroll
        for (int mf = 0; mf < 4; ++mf) {
            const int mblk = mblk0 + mf;
            #pragma unroll
            for (int r = 0; r < 4; ++r) {
                const int lane_r = lh * 4 + r;
                #pragma unroll
                for (int nf = 0; nf < 3; ++nf) {
                    const int c = bn + wc * 48 + nf * 16 + lr;
                    const int idx = (mblk * 24 + (c >> 5)) * 512
                                  + ((c >> 3) & 3) * 128 + lane_r * 8 + (c & 7);
                    const float v = fmaxf(acc[mf][nf][r], 0.f);
                    u16 h, l; split2(v, h, l);
                    Oh[idx] = h; Ol[idx] = l;
                }
            }
        }
        return;
    }

    // ---------------- MODE 1: phase 2 (adjacency GEMM in-LDS) ----------------
    const u16* adjL = lds + 12288;   // adj [128 node][16 chunks swizzled]
    u16* hwT = lds;                  // H^T [96 c][128 node] swizzled (B bufs dead)

    // write HI halves of H^T; keep LO in registers
    u16x4 lv[4][3];
    #pragma unroll
    for (int mf = 0; mf < 4; ++mf) {
        const int node0 = wr * 64 + mf * 16 + lh * 4;
        #pragma unroll
        for (int nf = 0; nf < 3; ++nf) {
            const int c = wc * 48 + nf * 16 + lr;
            u16x4 hv;
            #pragma unroll
            for (int r = 0; r < 4; ++r) {
                u16 h, l; split2(acc[mf][nf][r], h, l);
                hv[r] = h; lv[mf][nf][r] = l;
            }
            *(u16x4*)&hwT[c * 128 + (((node0 >> 3) ^ (c & 7)) << 3) + (node0 & 7)] = hv;
        }
    }
    asm volatile("s_waitcnt lgkmcnt(0)" ::: "memory");
    __builtin_amdgcn_s_barrier();
    __builtin_amdgcn_sched_barrier(0);

    f32x4 acc2[4][3];
    #pragma unroll
    for (int i = 0; i < 4; ++i)
        #pragma unroll
        for (int j = 0; j < 3; ++j)
            acc2[i][j] = (f32x4){0.f, 0.f, 0.f, 0.f};

    #pragma unroll
    for (int pass = 0; pass < 2; ++pass) {
        if (pass == 1) {
            #pragma unroll
            for (int mf = 0; mf < 4; ++mf) {
                const int node0 = wr * 64 + mf * 16 + lh * 4;
                #pragma unroll
                for (int nf = 0; nf < 3; ++nf) {
                    const int c = wc * 48 + nf * 16 + lr;
                    *(u16x4*)&hwT[c * 128 + (((node0 >> 3) ^ (c & 7)) << 3) + (node0 & 7)] = lv[mf][nf];
                }
            }
            asm volatile("s_waitcnt lgkmcnt(0)" ::: "memory");
            __builtin_amdgcn_s_barrier();
            __builtin_amdgcn_sched_barrier(0);
        }
        #pragma unroll
        for (int ks = 0; ks < 4; ++ks) {
            short8 af[4], bf[3];
            #pragma unroll
            for (int f = 0; f < 4; ++f) {
                const int node = wr * 64 + f * 16 + lr;
                af[f] = *(const short8*)&adjL[node * 128 + (((ks * 4 + lh) ^ (node & 7)) << 3)];
            }
            #pragma unroll
            for (int f = 0; f < 3; ++f) {
                const int c = wc * 48 + f * 16 + lr;
                bf[f] = *(const short8*)&hwT[c * 128 + (((ks * 4 + lh) ^ (c & 7)) << 3)];
            }
            #pragma unroll
            for (int mf = 0; mf < 4; ++mf)
                #pragma unroll
                for (int nf = 0; nf < 3; ++nf)
                    acc2[mf][nf] = __builtin_amdgcn_mfma_f32_16x16x32_bf16(af[mf], bf[nf], acc2[mf][nf], 0, 0, 0);
        }
        if (pass == 0) {
            asm volatile("s_waitcnt lgkmcnt(0)" ::: "memory");
            __builtin_amdgcn_s_barrier();
            __builtin_amdgcn_sched_barrier(0);
        }
    }

    // epilogue: out = relu(acc2*inv + bias) + X_in; split; store (FRAG layout)
    #pragma unroll
    for (int mf = 0; mf < 4; ++mf) {
        const int mblk = mblk0 + mf;
        #pragma unroll
        for (int r = 0; r < 4; ++r) {
            const int node = wr * 64 + mf * 16 + lh * 4 + r;
            const int lane_r = lh * 4 + r;
            const float inv = invden[bmb * N_ + node];
            #pragma unroll
            for (int nf = 0; nf < 3; ++nf) {
                const int c = bn + wc * 48 + nf * 16 + lr;
                const int idx = (mblk * 24 + (c >> 5)) * 512
                              + ((c >> 3) & 3) * 128 + lane_r * 8 + (c & 7);
                float v = fmaxf(acc2[mf][nf][r] * inv + bias[c], 0.f);
                v += bf2f(Ah[idx]) + bf2f(Al[idx]);   // residual = A-source
                u16 h, l; split2(v, h, l);
                Oh[idx] = h; Ol[idx] = l;
            }
        }
    }
}

// ---------------------------------------------------------------------------
__global__ __launch_bounds__(192)
void gcn_target_kernel(const u16* __restrict__ Xh, const u16* __restrict__ Xl,
                       const int* __restrict__ gspan, float* __restrict__ gt) {
    const int b = blockIdx.x;
    const int s = gspan[b * 2 + 0];
    const int e = gspan[b * 2 + 1];
    const int d4 = threadIdx.x;
    float4 acc = make_float4(0.f, 0.f, 0.f, 0.f);
    for (int n = s; n < e; ++n) {
        const int idx = fragIdx(b * N_ + n, d4 * 4);
        const u16x4 h = *(const u16x4*)(Xh + idx);
        const u16x4 l = *(const u16x4*)(Xl + idx);
        acc.x += bf2f(h[0]) + bf2f(l[0]);
        acc.y += bf2f(h[1]) + bf2f(l[1]);
        acc.z += bf2f(h[2]) + bf2f(l[2]);
        acc.w += bf2f(h[3]) + bf2f(l[3]);
    }
    reinterpret_cast<float4*>(gt + (size_t)b * D_)[d4] = acc;
}

// ---------------------------------------------------------------------------
__global__ __launch_bounds__(256)
void head_kernel(const float* __restrict__ tmax, const float* __restrict__ gt,
                 const float* __restrict__ fcW, const float* __restrict__ fcb,
                 float* __restrict__ out) {
    const int b = blockIdx.x;
    const int t = threadIdx.x;
    float p0 = 0.f, p1 = 0.f, p2 = 0.f;
    for (int i = t; i < 2 * D_; i += 256) {
        const float v = (i < D_) ? tmax[(size_t)b * D_ + i] : gt[(size_t)b * D_ + i - D_];
        p0 += v * fcW[i * 3 + 0];
        p1 += v * fcW[i * 3 + 1];
        p2 += v * fcW[i * 3 + 2];
    }
    #pragma unroll
    for (int off = 32; off; off >>= 1) {
        p0 += __shfl_down(p0, off, 64);
        p1 += __shfl_down(p1, off, 64);
        p2 += __shfl_down(p2, off, 64);
    }
    __shared__ float red[4][3];
    const int wv = t >> 6;
    if ((t & 63) == 0) { red[wv][0] = p0; red[wv][1] = p1; red[wv][2] = p2; }
    __syncthreads();
    if (t == 0) {
        #pragma unroll
        for (int o = 0; o < 3; ++o) {
            const float s = red[0][o] + red[1][o] + red[2][o] + red[3][o] + fcb[o];
            out[b * 3 + o] = tanhf(s);
        }
    }
}

// ---------------------------------------------------------------------------
extern "C" void kernel_launch(void* const* d_in, const int* in_sizes, int n_in,
                              void* d_out, int out_size, void* d_ws, size_t ws_size,
                              hipStream_t stream) {
    const float* se   = (const float*)d_in[0];
    const float* dg   = (const float*)d_in[1];
    const float* dg1  = (const float*)d_in[2];
    const float* Wp   = (const float*)d_in[3];
    const float* Wg[3] = {(const float*)d_in[4], (const float*)d_in[6], (const float*)d_in[8]};
    const float* bg[3] = {(const float*)d_in[5], (const float*)d_in[7], (const float*)d_in[9]};
    const float* fcW  = (const float*)d_in[10];
    const float* fcb  = (const float*)d_in[11];
    const int*   tspan  = (const int*)d_in[12];
    const int*   nspans = (const int*)d_in[13];
    const int*   gspan  = (const int*)d_in[14];
    float* out = (float*)d_out;

    // workspace layout (u16 units unless noted)
    u16* us   = (u16*)d_ws;
    u16* X0h  = us;                        // 8192*768 each (FRAG layout)
    u16* X0l  = X0h + 6291456;
    u16* X1h  = X0l + 6291456;
    u16* X1l  = X1h + 6291456;
    u16* TH   = X1l + 6291456;             // tmps hi/lo (FRAG layout)
    u16* TL   = TH  + 6291456;
    u16* WTh  = TL  + 6291456;             // 4*768*768
    u16* WTl  = WTh + 2359296;
    u16* ADJ  = WTl + 2359296;             // 64*128*128
    float* INV = (float*)(ADJ + 1048576);  // 8192
    float* TMX = INV + 8192;               // 64*768
    float* GT  = TMX + 49152;              // 64*768

    // Stage A: ragged prep
    span_split_kernel<<<B_ * N_, 192, 0, stream>>>(se, nspans, TH, TL);
    target_max_kernel<<<B_, 192, 0, stream>>>(se, tspan, TMX);
    adj_kernel<<<B_ * N_, 128, 0, stream>>>(dg, dg1, ADJ, INV);
    wsplit_kernel<<<dim3(12, 12, 4), 256, 0, stream>>>(Wp, Wg[0], Wg[1], Wg[2], WTh, WTl);

    // Stage B: X0 = relu(tmps @ W_proj)   (512 blocks: 64 row-panels x 8 col-96)
    gemm_fused<0><<<512, 256, 0, stream>>>(TH, TL, WTh, WTl,
                                           nullptr, nullptr, nullptr, X0h, X0l);

    // Stage C: 3 fused GCN layers (ping-pong X0 <-> X1)
    const u16* inh[3] = {X0h, X1h, X0h};
    const u16* inl[3] = {X0l, X1l, X0l};
    u16* outh[3] = {X1h, X0h, X1h};
    u16* outl[3] = {X1l, X0l, X1l};
    for (int l = 0; l < 3; ++l) {
        const size_t wo = (size_t)(l + 1) * D_ * D_;
        gemm_fused<1><<<512, 256, 0, stream>>>(inh[l], inl[l], WTh + wo, WTl + wo,
                                               ADJ, INV, bg[l], outh[l], outl[l]);
    }

    // Stage D: ragged node-span sum + head (final X lives in X1)
    gcn_target_kernel<<<B_, 192, 0, stream>>>(X1h, X1l, gspan, GT);
    head_kernel<<<B_, 256, 0, stream>>>(TMX, GT, fcW, fcb, out);
}

// Round 9
// 171.049 us; speedup vs baseline: 1.5985x; 1.1427x over previous
//
#include <hip/hip_runtime.h>
#include <float.h>
#include <math.h>

typedef __attribute__((ext_vector_type(8))) short short8;
typedef __attribute__((ext_vector_type(4))) float f32x4;
typedef __attribute__((ext_vector_type(4))) unsigned short u16x4;
typedef unsigned short u16;
typedef unsigned int u32;

constexpr int B_ = 64, S_ = 512, N_ = 128, D_ = 768;

// ---------------------------------------------------------------------------
__device__ inline void split2h(float x, u16& h, u16& l) {
    _Float16 hh = (_Float16)x;
    _Float16 ll = (_Float16)(x - (float)hh);
    h = __builtin_bit_cast(u16, hh);
    l = __builtin_bit_cast(u16, ll);
}
__device__ inline u16 f2h(float x) {
    _Float16 hh = (_Float16)x;
    return __builtin_bit_cast(u16, hh);
}
__device__ inline float h2f(u16 h) {
    return (float)__builtin_bit_cast(_Float16, h);
}

__device__ inline void gload_lds16(const u16* g, u16* s) {
    __builtin_amdgcn_global_load_lds(
        (const __attribute__((address_space(1))) u32*)g,
        (__attribute__((address_space(3))) u32*)s, 16, 0, 0);
}

// Fragment-major layout for activation matrices [M][768]:
// u16 index of (row, col) = ((row>>4)*24 + (col>>5))*512
//                         + ((col>>3)&3)*128 + (row&15)*8 + (col&7)
__device__ inline int fragIdx(int row, int col) {
    return ((row >> 4) * 24 + (col >> 5)) * 512 + ((col >> 3) & 3) * 128
         + (row & 15) * 8 + (col & 7);
}

// ---------------------------------------------------------------------------
// tmps[b,n,:] = sum_{r=s+1..e} se[b,r,:]  -> split fp16 hi/lo, FRAG layout
__global__ __launch_bounds__(192)
void span_split_kernel(const float* __restrict__ se, const int* __restrict__ spans,
                       u16* __restrict__ th, u16* __restrict__ tl) {
    const int bn = blockIdx.x;
    const int b  = bn >> 7;
    const int s  = spans[bn * 2 + 0];
    const int e  = spans[bn * 2 + 1];
    const float* base = se + (size_t)b * S_ * D_;
    const int d4 = threadIdx.x;
    float4 acc = make_float4(0.f, 0.f, 0.f, 0.f);
    for (int r = s + 1; r <= e; ++r) {
        const float4 v = reinterpret_cast<const float4*>(base + (size_t)r * D_)[d4];
        acc.x += v.x; acc.y += v.y; acc.z += v.z; acc.w += v.w;
    }
    u16x4 hv, lv;
    u16 hh, ll;
    split2h(acc.x, hh, ll); hv[0] = hh; lv[0] = ll;
    split2h(acc.y, hh, ll); hv[1] = hh; lv[1] = ll;
    split2h(acc.z, hh, ll); hv[2] = hh; lv[2] = ll;
    split2h(acc.w, hh, ll); hv[3] = hh; lv[3] = ll;
    const int idx = fragIdx(bn, d4 * 4);
    *(u16x4*)(th + idx) = hv;
    *(u16x4*)(tl + idx) = lv;
}

// ---------------------------------------------------------------------------
__global__ __launch_bounds__(192)
void target_max_kernel(const float* __restrict__ se, const int* __restrict__ tspan,
                       float* __restrict__ tmax) {
    const int b = blockIdx.x;
    const int s = tspan[b * 2 + 0];
    const int e = tspan[b * 2 + 1];
    const float* base = se + (size_t)b * S_ * D_;
    const int d4 = threadIdx.x;
    float4 m = make_float4(-FLT_MAX, -FLT_MAX, -FLT_MAX, -FLT_MAX);
    for (int r = s; r < e; ++r) {
        const float4 v = reinterpret_cast<const float4*>(base + (size_t)r * D_)[d4];
        m.x = fmaxf(m.x, v.x); m.y = fmaxf(m.y, v.y);
        m.z = fmaxf(m.z, v.z); m.w = fmaxf(m.w, v.w);
    }
    reinterpret_cast<float4*>(tmax + (size_t)b * D_)[d4] = m;
}

// ---------------------------------------------------------------------------
// adj = clamp(dg+dg1,1) -> fp16 (exact {0,1}) [b][n][k]; invden = 1/(rowsum+1e-7)
__global__ __launch_bounds__(128)
void adj_kernel(const float* __restrict__ dg, const float* __restrict__ dg1,
                u16* __restrict__ adj, float* __restrict__ invden) {
    const int row = blockIdx.x;
    const int t   = threadIdx.x;
    const size_t idx = (size_t)row * N_ + t;
    float a = dg[idx] + dg1[idx];
    a = (a >= 1.f) ? 1.f : a;
    adj[idx] = f2h(a);
    float w = a;
    #pragma unroll
    for (int off = 32; off; off >>= 1) w += __shfl_down(w, off, 64);
    __shared__ float ssum[2];
    if ((t & 63) == 0) ssum[t >> 6] = w;
    __syncthreads();
    if (t == 0) invden[row] = 1.f / (ssum[0] + ssum[1] + 1e-7f);
}

// ---------------------------------------------------------------------------
// Weights: W[k][n] (768x768) -> WT[n][k] single fp16. blockIdx.z = matrix.
__global__ __launch_bounds__(256)
void wsplit_kernel(const float* __restrict__ W0, const float* __restrict__ W1,
                   const float* __restrict__ W2, const float* __restrict__ W3,
                   u16* __restrict__ wth) {
    __shared__ float t[64][65];
    const int mi = blockIdx.z;
    const float* W = (mi == 0) ? W0 : (mi == 1) ? W1 : (mi == 2) ? W2 : W3;
    const int k0 = blockIdx.y * 64, n0 = blockIdx.x * 64;
    #pragma unroll 4
    for (int it = 0; it < 16; ++it) {
        const int lin = it * 256 + threadIdx.x;
        const int r = lin >> 6, c = lin & 63;
        t[r][c] = W[(size_t)(k0 + r) * D_ + n0 + c];
    }
    __syncthreads();
    u16* oh = wth + (size_t)mi * D_ * D_;
    #pragma unroll 4
    for (int it = 0; it < 16; ++it) {
        const int lin = it * 256 + threadIdx.x;
        const int r = lin >> 6, c = lin & 63;
        oh[(size_t)(n0 + r) * D_ + k0 + c] = f2h(t[c][r]);
    }
}

// ---------------------------------------------------------------------------
// Fused fp16 GEMM (A = hi/lo pair, W = single fp16, 2 MFMA products).
// 128x96 tile, 8 waves (4 row x 2 col, 32x48 each), 512 blocks (2/CU,
// 16 waves/CU). A: FRAG-layout global -> VGPR, dbuf 1 K-step ahead.
// B: LDS dbuf 2 x 6 KB, 64B rows of 4 chunks, phys chunk p = q ^ ((row>>1)&3)
// pre-applied on global source. adj: VGPRs (post-loop). hwT: 24 KB reusing
// the whole LDS after the K-loop (single fp16 pass).
// MODE 0: store relu(H) split fp16 hi/lo, FRAG layout.
// MODE 1: out = relu((adj[b]@H)*invden + bias) + X_in (FRAG layout).
template<int MODE>
__global__ __launch_bounds__(512, 4)
void gemm_fused(const u16* __restrict__ Ah, const u16* __restrict__ Al,
                const u16* __restrict__ Bh,
                const u16* __restrict__ ADJ, const float* __restrict__ invden,
                const float* __restrict__ bias,
                u16* __restrict__ Oh, u16* __restrict__ Ol) {
    __shared__ u16 lds[12288];   // 24 KB: B buf0 [0,3072), buf1 [3072,6144); hwT all
    const int tid  = threadIdx.x;
    const int lane = tid & 63, w = tid >> 6;     // 8 waves
    const int wr = w >> 1, wc = w & 1;           // 4 row x 2 col
    const int lr = lane & 15, lh = lane >> 4;

    int bid = blockIdx.x;
    bid = (bid & 7) * 64 + (bid >> 3);           // XCD swizzle (512 % 8 == 0)
    const int bnb = bid & 7, bmb = bid >> 3;
    const int bn = bnb * 96;

    // --- B staging: 6 instrs (16 rows x 64B each); wave w<6 stages group w ---
    // lane l -> row = w*16 + (l>>2), phys chunk l&3, logical q = (l&3)^((l>>3)&3)
    const int qch = (lane & 3) ^ ((lane >> 3) & 3);
    const u16* gBsrc = Bh + (size_t)(bn + w * 16 + (lane >> 2)) * 768 + qch * 8;

    // --- A frag bases: wave owns mblks mblk0, mblk0+1 ---
    const int mblk0 = bmb * 8 + wr * 2;
    const u16* gAh = Ah + (size_t)mblk0 * 12288 + lane * 8;
    const u16* gAl = Al + (size_t)mblk0 * 12288 + lane * 8;

    f32x4 acc[2][3];
    #pragma unroll
    for (int i = 0; i < 2; ++i)
        #pragma unroll
        for (int j = 0; j < 3; ++j)
            acc[i][j] = (f32x4){0.f, 0.f, 0.f, 0.f};

    short8 aA[4], aB[4];   // [0,1] hi mblk0/+1, [2,3] lo

    // prologue: tile 0
    if (w < 6) gload_lds16(gBsrc, lds + w * 512);
    #pragma unroll
    for (int mf = 0; mf < 2; ++mf) {
        asm volatile("global_load_dwordx4 %0, %1, off"
                     : "=v"(aA[mf]) : "v"(gAh + mf * 12288) : "memory");
        asm volatile("global_load_dwordx4 %0, %1, off"
                     : "=v"(aA[2 + mf]) : "v"(gAl + mf * 12288) : "memory");
    }

    const int pB = (lh ^ ((lr >> 1) & 3)) << 3;  // B frag phys chunk offset (u16)

#define GEMM_ITER(T, CUR, NXT)                                                \
    {                                                                         \
        const int t_ = (T);                                                   \
        if (t_ < 23) {                                                        \
            if (w < 6)                                                        \
                gload_lds16(gBsrc + (t_ + 1) * 32,                            \
                            lds + ((t_ + 1) & 1) * 3072 + w * 512);           \
            _Pragma("unroll")                                                 \
            for (int mf = 0; mf < 2; ++mf) {                                  \
                asm volatile("global_load_dwordx4 %0, %1, off"                \
                    : "=v"(NXT[mf])                                           \
                    : "v"(gAh + mf * 12288 + (t_ + 1) * 512) : "memory");     \
                asm volatile("global_load_dwordx4 %0, %1, off"                \
                    : "=v"(NXT[2 + mf])                                       \
                    : "v"(gAl + mf * 12288 + (t_ + 1) * 512) : "memory");     \
            }                                                                 \
            if (w < 6) asm volatile("s_waitcnt vmcnt(5)" ::: "memory");       \
            else       asm volatile("s_waitcnt vmcnt(4)" ::: "memory");       \
        } else {                                                              \
            asm volatile("s_waitcnt vmcnt(0)" ::: "memory");                  \
        }                                                                     \
        __builtin_amdgcn_s_barrier();                                         \
        __builtin_amdgcn_sched_barrier(0);                                    \
        const u16* Lb = lds + (t_ & 1) * 3072;                                \
        short8 bh4[3];                                                        \
        _Pragma("unroll")                                                     \
        for (int f = 0; f < 3; ++f)                                           \
            bh4[f] = *(const short8*)&Lb[(wc * 48 + f * 16 + lr) * 32 + pB];  \
        __builtin_amdgcn_s_setprio(1);                                        \
        _Pragma("unroll")                                                     \
        for (int mf = 0; mf < 2; ++mf)                                        \
            _Pragma("unroll")                                                 \
            for (int nf = 0; nf < 3; ++nf) {                                  \
                acc[mf][nf] = __builtin_amdgcn_mfma_f32_16x16x32_f16(CUR[mf], bh4[nf], acc[mf][nf], 0, 0, 0);     \
                acc[mf][nf] = __builtin_amdgcn_mfma_f32_16x16x32_f16(CUR[2 + mf], bh4[nf], acc[mf][nf], 0, 0, 0); \
            }                                                                 \
        __builtin_amdgcn_s_setprio(0);                                        \
        asm volatile("s_waitcnt lgkmcnt(0)" ::: "memory");                    \
        __builtin_amdgcn_s_barrier();                                         \
    }

    for (int tt = 0; tt < 12; ++tt) {
        GEMM_ITER(2 * tt,     aA, aB)
        GEMM_ITER(2 * tt + 1, aB, aA)
    }
#undef GEMM_ITER

    if (MODE == 0) {
        #pragma unroll
        for (int mf = 0; mf < 2; ++mf) {
            const int mblk = mblk0 + mf;
            #pragma unroll
            for (int r = 0; r < 4; ++r) {
                const int lane_r = lh * 4 + r;
                #pragma unroll
                for (int nf = 0; nf < 3; ++nf) {
                    const int c = bn + wc * 48 + nf * 16 + lr;
                    const int idx = (mblk * 24 + (c >> 5)) * 512
                                  + ((c >> 3) & 3) * 128 + lane_r * 8 + (c & 7);
                    const float v = fmaxf(acc[mf][nf][r], 0.f);
                    u16 h, l; split2h(v, h, l);
                    Oh[idx] = h; Ol[idx] = l;
                }
            }
        }
        return;
    }

    // ---------------- MODE 1: phase 2 (adjacency GEMM) ----------------------
    // adj fragments straight to VGPRs (once per block; outside the hot loop)
    const u16* adjb = ADJ + (size_t)bmb * (N_ * N_);
    short8 adjr[8];
    #pragma unroll
    for (int mf = 0; mf < 2; ++mf)
        #pragma unroll
        for (int ks = 0; ks < 4; ++ks)
            adjr[mf * 4 + ks] = *(const short8*)(adjb +
                (size_t)(wr * 32 + mf * 16 + lr) * 128 + ks * 32 + lh * 8);

    // write H^T (single fp16) into LDS [c 96][node 128], chunk-swizzled
    u16* hwT = lds;
    #pragma unroll
    for (int mf = 0; mf < 2; ++mf) {
        const int node0 = wr * 32 + mf * 16 + lh * 4;
        #pragma unroll
        for (int nf = 0; nf < 3; ++nf) {
            const int c = wc * 48 + nf * 16 + lr;
            u16x4 hv;
            #pragma unroll
            for (int r = 0; r < 4; ++r) hv[r] = f2h(acc[mf][nf][r]);
            *(u16x4*)&hwT[c * 128 + (((node0 >> 3) ^ (c & 7)) << 3) + (node0 & 7)] = hv;
        }
    }
    asm volatile("s_waitcnt lgkmcnt(0)" ::: "memory");
    __builtin_amdgcn_s_barrier();
    __builtin_amdgcn_sched_barrier(0);

    f32x4 acc2[2][3];
    #pragma unroll
    for (int i = 0; i < 2; ++i)
        #pragma unroll
        for (int j = 0; j < 3; ++j)
            acc2[i][j] = (f32x4){0.f, 0.f, 0.f, 0.f};

    #pragma unroll
    for (int ks = 0; ks < 4; ++ks) {
        short8 bf[3];
        #pragma unroll
        for (int f = 0; f < 3; ++f) {
            const int c = wc * 48 + f * 16 + lr;
            bf[f] = *(const short8*)&hwT[c * 128 + (((ks * 4 + lh) ^ (c & 7)) << 3)];
        }
        #pragma unroll
        for (int mf = 0; mf < 2; ++mf)
            #pragma unroll
            for (int nf = 0; nf < 3; ++nf)
                acc2[mf][nf] = __builtin_amdgcn_mfma_f32_16x16x32_f16(adjr[mf * 4 + ks], bf[nf], acc2[mf][nf], 0, 0, 0);
    }

    // epilogue: out = relu(acc2*inv + bias) + X_in; split fp16; store FRAG
    #pragma unroll
    for (int mf = 0; mf < 2; ++mf) {
        const int mblk = mblk0 + mf;
        #pragma unroll
        for (int r = 0; r < 4; ++r) {
            const int node = wr * 32 + mf * 16 + lh * 4 + r;
            const int lane_r = lh * 4 + r;
            const float inv = invden[bmb * N_ + node];
            #pragma unroll
            for (int nf = 0; nf < 3; ++nf) {
                const int c = bn + wc * 48 + nf * 16 + lr;
                const int idx = (mblk * 24 + (c >> 5)) * 512
                              + ((c >> 3) & 3) * 128 + lane_r * 8 + (c & 7);
                float v = fmaxf(acc2[mf][nf][r] * inv + bias[c], 0.f);
                v += h2f(Ah[idx]) + h2f(Al[idx]);   // residual = A-source
                u16 h, l; split2h(v, h, l);
                Oh[idx] = h; Ol[idx] = l;
            }
        }
    }
}

// ---------------------------------------------------------------------------
__global__ __launch_bounds__(192)
void gcn_target_kernel(const u16* __restrict__ Xh, const u16* __restrict__ Xl,
                       const int* __restrict__ gspan, float* __restrict__ gt) {
    const int b = blockIdx.x;
    const int s = gspan[b * 2 + 0];
    const int e = gspan[b * 2 + 1];
    const int d4 = threadIdx.x;
    float4 acc = make_float4(0.f, 0.f, 0.f, 0.f);
    for (int n = s; n < e; ++n) {
        const int idx = fragIdx(b * N_ + n, d4 * 4);
        const u16x4 h = *(const u16x4*)(Xh + idx);
        const u16x4 l = *(const u16x4*)(Xl + idx);
        acc.x += h2f(h[0]) + h2f(l[0]);
        acc.y += h2f(h[1]) + h2f(l[1]);
        acc.z += h2f(h[2]) + h2f(l[2]);
        acc.w += h2f(h[3]) + h2f(l[3]);
    }
    reinterpret_cast<float4*>(gt + (size_t)b * D_)[d4] = acc;
}

// ---------------------------------------------------------------------------
__global__ __launch_bounds__(256)
void head_kernel(const float* __restrict__ tmax, const float* __restrict__ gt,
                 const float* __restrict__ fcW, const float* __restrict__ fcb,
                 float* __restrict__ out) {
    const int b = blockIdx.x;
    const int t = threadIdx.x;
    float p0 = 0.f, p1 = 0.f, p2 = 0.f;
    for (int i = t; i < 2 * D_; i += 256) {
        const float v = (i < D_) ? tmax[(size_t)b * D_ + i] : gt[(size_t)b * D_ + i - D_];
        p0 += v * fcW[i * 3 + 0];
        p1 += v * fcW[i * 3 + 1];
        p2 += v * fcW[i * 3 + 2];
    }
    #pragma unroll
    for (int off = 32; off; off >>= 1) {
        p0 += __shfl_down(p0, off, 64);
        p1 += __shfl_down(p1, off, 64);
        p2 += __shfl_down(p2, off, 64);
    }
    __shared__ float red[4][3];
    const int wv = t >> 6;
    if ((t & 63) == 0) { red[wv][0] = p0; red[wv][1] = p1; red[wv][2] = p2; }
    __syncthreads();
    if (t == 0) {
        #pragma unroll
        for (int o = 0; o < 3; ++o) {
            const float s = red[0][o] + red[1][o] + red[2][o] + red[3][o] + fcb[o];
            out[b * 3 + o] = tanhf(s);
        }
    }
}

// ---------------------------------------------------------------------------
extern "C" void kernel_launch(void* const* d_in, const int* in_sizes, int n_in,
                              void* d_out, int out_size, void* d_ws, size_t ws_size,
                              hipStream_t stream) {
    const float* se   = (const float*)d_in[0];
    const float* dg   = (const float*)d_in[1];
    const float* dg1  = (const float*)d_in[2];
    const float* Wp   = (const float*)d_in[3];
    const float* Wg[3] = {(const float*)d_in[4], (const float*)d_in[6], (const float*)d_in[8]};
    const float* bg[3] = {(const float*)d_in[5], (const float*)d_in[7], (const float*)d_in[9]};
    const float* fcW  = (const float*)d_in[10];
    const float* fcb  = (const float*)d_in[11];
    const int*   tspan  = (const int*)d_in[12];
    const int*   nspans = (const int*)d_in[13];
    const int*   gspan  = (const int*)d_in[14];
    float* out = (float*)d_out;

    // workspace layout (u16 units unless noted)
    u16* us   = (u16*)d_ws;
    u16* X0h  = us;                        // 8192*768 each (FRAG layout)
    u16* X0l  = X0h + 6291456;
    u16* X1h  = X0l + 6291456;
    u16* X1l  = X1h + 6291456;
    u16* TH   = X1l + 6291456;             // tmps hi/lo (FRAG layout)
    u16* TL   = TH  + 6291456;
    u16* WTh  = TL  + 6291456;             // 4*768*768 fp16 (single)
    u16* ADJ  = WTh + 2359296;             // 64*128*128 fp16
    float* INV = (float*)(ADJ + 1048576);  // 8192
    float* TMX = INV + 8192;               // 64*768
    float* GT  = TMX + 49152;              // 64*768

    // Stage A: ragged prep
    span_split_kernel<<<B_ * N_, 192, 0, stream>>>(se, nspans, TH, TL);
    target_max_kernel<<<B_, 192, 0, stream>>>(se, tspan, TMX);
    adj_kernel<<<B_ * N_, 128, 0, stream>>>(dg, dg1, ADJ, INV);
    wsplit_kernel<<<dim3(12, 12, 4), 256, 0, stream>>>(Wp, Wg[0], Wg[1], Wg[2], WTh);

    // Stage B: X0 = relu(tmps @ W_proj)   (512 blocks: 64 row-panels x 8 col-96)
    gemm_fused<0><<<512, 512, 0, stream>>>(TH, TL, WTh,
                                           nullptr, nullptr, nullptr, X0h, X0l);

    // Stage C: 3 fused GCN layers (ping-pong X0 <-> X1)
    const u16* inh[3] = {X0h, X1h, X0h};
    const u16* inl[3] = {X0l, X1l, X0l};
    u16* outh[3] = {X1h, X0h, X1h};
    u16* outl[3] = {X1l, X0l, X1l};
    for (int l = 0; l < 3; ++l) {
        const size_t wo = (size_t)(l + 1) * D_ * D_;
        gemm_fused<1><<<512, 512, 0, stream>>>(inh[l], inl[l], WTh + wo,
                                               ADJ, INV, bg[l], outh[l], outl[l]);
    }

    // Stage D: ragged node-span sum + head (final X lives in X1)
    gcn_target_kernel<<<B_, 192, 0, stream>>>(X1h, X1l, gspan, GT);
    head_kernel<<<B_, 256, 0, stream>>>(TMX, GT, fcW, fcb, out);
}

// Round 10
// 169.805 us; speedup vs baseline: 1.6102x; 1.0073x over previous
//
#include <hip/hip_runtime.h>
#include <float.h>
#include <math.h>

typedef __attribute__((ext_vector_type(8))) short short8;
typedef __attribute__((ext_vector_type(4))) float f32x4;
typedef __attribute__((ext_vector_type(4))) unsigned short u16x4;
typedef unsigned short u16;
typedef unsigned int u32;

constexpr int B_ = 64, S_ = 512, N_ = 128, D_ = 768;

// ---------------------------------------------------------------------------
__device__ inline void split2h(float x, u16& h, u16& l) {
    _Float16 hh = (_Float16)x;
    _Float16 ll = (_Float16)(x - (float)hh);
    h = __builtin_bit_cast(u16, hh);
    l = __builtin_bit_cast(u16, ll);
}
__device__ inline u16 f2h(float x) {
    _Float16 hh = (_Float16)x;
    return __builtin_bit_cast(u16, hh);
}
__device__ inline float h2f(u16 h) {
    return (float)__builtin_bit_cast(_Float16, h);
}

__device__ inline void gload_lds16(const u16* g, u16* s) {
    __builtin_amdgcn_global_load_lds(
        (const __attribute__((address_space(1))) u32*)g,
        (__attribute__((address_space(3))) u32*)s, 16, 0, 0);
}

// Fragment-major layout for activation matrices [M][768]:
// u16 index of (row, col) = ((row>>4)*24 + (col>>5))*512
//                         + ((col>>3)&3)*128 + (row&15)*8 + (col&7)
__device__ inline int fragIdx(int row, int col) {
    return ((row >> 4) * 24 + (col >> 5)) * 512 + ((col >> 3) & 3) * 128
         + (row & 15) * 8 + (col & 7);
}

// ---------------------------------------------------------------------------
// tmps[b,n,:] = sum_{r=s+1..e} se[b,r,:]  -> split fp16 hi/lo, FRAG layout
__global__ __launch_bounds__(192)
void span_split_kernel(const float* __restrict__ se, const int* __restrict__ spans,
                       u16* __restrict__ th, u16* __restrict__ tl) {
    const int bn = blockIdx.x;
    const int b  = bn >> 7;
    const int s  = spans[bn * 2 + 0];
    const int e  = spans[bn * 2 + 1];
    const float* base = se + (size_t)b * S_ * D_;
    const int d4 = threadIdx.x;
    float4 acc = make_float4(0.f, 0.f, 0.f, 0.f);
    for (int r = s + 1; r <= e; ++r) {
        const float4 v = reinterpret_cast<const float4*>(base + (size_t)r * D_)[d4];
        acc.x += v.x; acc.y += v.y; acc.z += v.z; acc.w += v.w;
    }
    u16x4 hv, lv;
    u16 hh, ll;
    split2h(acc.x, hh, ll); hv[0] = hh; lv[0] = ll;
    split2h(acc.y, hh, ll); hv[1] = hh; lv[1] = ll;
    split2h(acc.z, hh, ll); hv[2] = hh; lv[2] = ll;
    split2h(acc.w, hh, ll); hv[3] = hh; lv[3] = ll;
    const int idx = fragIdx(bn, d4 * 4);
    *(u16x4*)(th + idx) = hv;
    *(u16x4*)(tl + idx) = lv;
}

// ---------------------------------------------------------------------------
__global__ __launch_bounds__(192)
void target_max_kernel(const float* __restrict__ se, const int* __restrict__ tspan,
                       float* __restrict__ tmax) {
    const int b = blockIdx.x;
    const int s = tspan[b * 2 + 0];
    const int e = tspan[b * 2 + 1];
    const float* base = se + (size_t)b * S_ * D_;
    const int d4 = threadIdx.x;
    float4 m = make_float4(-FLT_MAX, -FLT_MAX, -FLT_MAX, -FLT_MAX);
    for (int r = s; r < e; ++r) {
        const float4 v = reinterpret_cast<const float4*>(base + (size_t)r * D_)[d4];
        m.x = fmaxf(m.x, v.x); m.y = fmaxf(m.y, v.y);
        m.z = fmaxf(m.z, v.z); m.w = fmaxf(m.w, v.w);
    }
    reinterpret_cast<float4*>(tmax + (size_t)b * D_)[d4] = m;
}

// ---------------------------------------------------------------------------
// adj = clamp(dg+dg1,1) -> fp16 (exact {0,1}) [b][n][k]; invden = 1/(rowsum+1e-7)
__global__ __launch_bounds__(128)
void adj_kernel(const float* __restrict__ dg, const float* __restrict__ dg1,
                u16* __restrict__ adj, float* __restrict__ invden) {
    const int row = blockIdx.x;
    const int t   = threadIdx.x;
    const size_t idx = (size_t)row * N_ + t;
    float a = dg[idx] + dg1[idx];
    a = (a >= 1.f) ? 1.f : a;
    adj[idx] = f2h(a);
    float w = a;
    #pragma unroll
    for (int off = 32; off; off >>= 1) w += __shfl_down(w, off, 64);
    __shared__ float ssum[2];
    if ((t & 63) == 0) ssum[t >> 6] = w;
    __syncthreads();
    if (t == 0) invden[row] = 1.f / (ssum[0] + ssum[1] + 1e-7f);
}

// ---------------------------------------------------------------------------
// Weights: W[k][n] (768x768) -> WT[n][k] single fp16. blockIdx.z = matrix.
__global__ __launch_bounds__(256)
void wsplit_kernel(const float* __restrict__ W0, const float* __restrict__ W1,
                   const float* __restrict__ W2, const float* __restrict__ W3,
                   u16* __restrict__ wth) {
    __shared__ float t[64][65];
    const int mi = blockIdx.z;
    const float* W = (mi == 0) ? W0 : (mi == 1) ? W1 : (mi == 2) ? W2 : W3;
    const int k0 = blockIdx.y * 64, n0 = blockIdx.x * 64;
    #pragma unroll 4
    for (int it = 0; it < 16; ++it) {
        const int lin = it * 256 + threadIdx.x;
        const int r = lin >> 6, c = lin & 63;
        t[r][c] = W[(size_t)(k0 + r) * D_ + n0 + c];
    }
    __syncthreads();
    u16* oh = wth + (size_t)mi * D_ * D_;
    #pragma unroll 4
    for (int it = 0; it < 16; ++it) {
        const int lin = it * 256 + threadIdx.x;
        const int r = lin >> 6, c = lin & 63;
        oh[(size_t)(n0 + r) * D_ + k0 + c] = f2h(t[c][r]);
    }
}

// ---------------------------------------------------------------------------
// Fused fp16 GEMM (A = hi/lo pair, W = single fp16, 2 MFMA products).
// 128x96 tile, 8 waves (4x2), 512 blocks (2/CU, 16 waves/CU).
// Single-barrier K-loop: A regs triple-buffered (loads 2 iters ahead),
// B LDS tri-buffered (3 x 6 KB; staged AFTER the barrier into the buffer
// freed 2 iters ago). Counted vmcnt, no mid-loop drains, no 2nd barrier.
// MODE 0: store relu(H) split fp16 hi/lo, FRAG layout.
// MODE 1: out = relu((adj[b]@H)*invden + bias) + X_in (FRAG layout);
//   adj in VGPRs post-loop; hwT (24 KB) reuses LDS after a drain barrier.
template<int MODE>
__global__ __launch_bounds__(512, 4)
void gemm_fused(const u16* __restrict__ Ah, const u16* __restrict__ Al,
                const u16* __restrict__ Bh,
                const u16* __restrict__ ADJ, const float* __restrict__ invden,
                const float* __restrict__ bias,
                u16* __restrict__ Oh, u16* __restrict__ Ol) {
    __shared__ u16 lds[12288];   // 24 KB: B tri-buf [0,9216); hwT uses [0,12288)
    const int tid  = threadIdx.x;
    const int lane = tid & 63, w = tid >> 6;     // 8 waves
    const int wr = w >> 1, wc = w & 1;           // 4 row x 2 col
    const int lr = lane & 15, lh = lane >> 4;

    int bid = blockIdx.x;
    bid = (bid & 7) * 64 + (bid >> 3);           // XCD swizzle (512 % 8 == 0)
    const int bnb = bid & 7, bmb = bid >> 3;
    const int bn = bnb * 96;

    // --- B staging: wave w<6 stages one 1KB group per tile ---
    // lane l -> row = w*16 + (l>>2), phys chunk l&3, logical q = (l&3)^((l>>3)&3)
    const int qch = (lane & 3) ^ ((lane >> 3) & 3);
    const u16* gBsrc = Bh + (size_t)(bn + w * 16 + (lane >> 2)) * 768 + qch * 8;

    // --- A frag bases: wave owns mblks mblk0, mblk0+1 ---
    const int mblk0 = bmb * 8 + wr * 2;
    const u16* gAh = Ah + (size_t)mblk0 * 12288 + lane * 8;
    const u16* gAl = Al + (size_t)mblk0 * 12288 + lane * 8;

    f32x4 acc[2][3];
    #pragma unroll
    for (int i = 0; i < 2; ++i)
        #pragma unroll
        for (int j = 0; j < 3; ++j)
            acc[i][j] = (f32x4){0.f, 0.f, 0.f, 0.f};

    short8 aS0[4], aS1[4], aS2[4];   // 3 A-sets: [0,1] hi, [2,3] lo

    // prologue (issue order matters for vmcnt counting): A0, B0, B1, A1
    #pragma unroll
    for (int mf = 0; mf < 2; ++mf) {
        asm volatile("global_load_dwordx4 %0, %1, off"
                     : "=v"(aS0[mf]) : "v"(gAh + mf * 12288) : "memory");
        asm volatile("global_load_dwordx4 %0, %1, off"
                     : "=v"(aS0[2 + mf]) : "v"(gAl + mf * 12288) : "memory");
    }
    if (w < 6) {
        gload_lds16(gBsrc, lds + w * 512);                 // B0 -> buf0
        gload_lds16(gBsrc + 32, lds + 3072 + w * 512);     // B1 -> buf1
    }
    #pragma unroll
    for (int mf = 0; mf < 2; ++mf) {
        asm volatile("global_load_dwordx4 %0, %1, off"
                     : "=v"(aS1[mf]) : "v"(gAh + mf * 12288 + 512) : "memory");
        asm volatile("global_load_dwordx4 %0, %1, off"
                     : "=v"(aS1[2 + mf]) : "v"(gAl + mf * 12288 + 512) : "memory");
    }

    const int pB = (lh ^ ((lr >> 1) & 3)) << 3;  // B frag phys chunk offset (u16)

// One K-step. C = compile-time phase (t_ % 3); CUR = A-set for tile t_;
// N2 = A-set receiving tile t_+2. Single barrier; stage after barrier.
#define GEMM_ITER(C, CUR, N2)                                                 \
    {                                                                         \
        const int t_ = 3 * tt + (C);                                          \
        if (t_ <= 21) {                                                       \
            _Pragma("unroll")                                                 \
            for (int mf = 0; mf < 2; ++mf) {                                  \
                asm volatile("global_load_dwordx4 %0, %1, off"                \
                    : "=v"(N2[mf])                                            \
                    : "v"(gAh + mf * 12288 + (t_ + 2) * 512) : "memory");     \
                asm volatile("global_load_dwordx4 %0, %1, off"                \
                    : "=v"(N2[2 + mf])                                        \
                    : "v"(gAl + mf * 12288 + (t_ + 2) * 512) : "memory");     \
            }                                                                 \
            if (w < 6) asm volatile("s_waitcnt vmcnt(9)" ::: "memory");       \
            else       asm volatile("s_waitcnt vmcnt(8)" ::: "memory");       \
        } else if (t_ == 22) {                                                \
            if (w < 6) asm volatile("s_waitcnt vmcnt(5)" ::: "memory");       \
            else       asm volatile("s_waitcnt vmcnt(4)" ::: "memory");       \
        } else {                                                              \
            asm volatile("s_waitcnt vmcnt(0)" ::: "memory");                  \
        }                                                                     \
        __builtin_amdgcn_s_barrier();                                         \
        __builtin_amdgcn_sched_barrier(0);                                    \
        if (t_ <= 21 && w < 6)                                                \
            gload_lds16(gBsrc + (t_ + 2) * 32,                                \
                        lds + (((C) + 2) % 3) * 3072 + w * 512);              \
        const u16* Lb = lds + ((C) % 3) * 3072;                               \
        short8 bh4[3];                                                        \
        _Pragma("unroll")                                                     \
        for (int f = 0; f < 3; ++f)                                           \
            bh4[f] = *(const short8*)&Lb[(wc * 48 + f * 16 + lr) * 32 + pB];  \
        __builtin_amdgcn_s_setprio(1);                                        \
        _Pragma("unroll")                                                     \
        for (int mf = 0; mf < 2; ++mf)                                        \
            _Pragma("unroll")                                                 \
            for (int nf = 0; nf < 3; ++nf) {                                  \
                acc[mf][nf] = __builtin_amdgcn_mfma_f32_16x16x32_f16(CUR[mf], bh4[nf], acc[mf][nf], 0, 0, 0);     \
                acc[mf][nf] = __builtin_amdgcn_mfma_f32_16x16x32_f16(CUR[2 + mf], bh4[nf], acc[mf][nf], 0, 0, 0); \
            }                                                                 \
        __builtin_amdgcn_s_setprio(0);                                        \
    }

    for (int tt = 0; tt < 8; ++tt) {
        GEMM_ITER(0, aS0, aS2)
        GEMM_ITER(1, aS1, aS0)
        GEMM_ITER(2, aS2, aS1)
    }
#undef GEMM_ITER

    if (MODE == 0) {
        #pragma unroll
        for (int mf = 0; mf < 2; ++mf) {
            const int mblk = mblk0 + mf;
            #pragma unroll
            for (int r = 0; r < 4; ++r) {
                const int lane_r = lh * 4 + r;
                #pragma unroll
                for (int nf = 0; nf < 3; ++nf) {
                    const int c = bn + wc * 48 + nf * 16 + lr;
                    const int idx = (mblk * 24 + (c >> 5)) * 512
                                  + ((c >> 3) & 3) * 128 + lane_r * 8 + (c & 7);
                    const float v = fmaxf(acc[mf][nf][r], 0.f);
                    u16 h, l; split2h(v, h, l);
                    Oh[idx] = h; Ol[idx] = l;
                }
            }
        }
        return;
    }

    // ---------------- MODE 1: phase 2 (adjacency GEMM) ----------------------
    // drain: all waves done reading buf2 before hwT overwrites LDS
    __builtin_amdgcn_s_barrier();
    __builtin_amdgcn_sched_barrier(0);

    // adj fragments straight to VGPRs (once per block)
    const u16* adjb = ADJ + (size_t)bmb * (N_ * N_);
    short8 adjr[8];
    #pragma unroll
    for (int mf = 0; mf < 2; ++mf)
        #pragma unroll
        for (int ks = 0; ks < 4; ++ks)
            adjr[mf * 4 + ks] = *(const short8*)(adjb +
                (size_t)(wr * 32 + mf * 16 + lr) * 128 + ks * 32 + lh * 8);

    // write H^T (single fp16) into LDS [c 96][node 128], chunk-swizzled
    u16* hwT = lds;
    #pragma unroll
    for (int mf = 0; mf < 2; ++mf) {
        const int node0 = wr * 32 + mf * 16 + lh * 4;
        #pragma unroll
        for (int nf = 0; nf < 3; ++nf) {
            const int c = wc * 48 + nf * 16 + lr;
            u16x4 hv;
            #pragma unroll
            for (int r = 0; r < 4; ++r) hv[r] = f2h(acc[mf][nf][r]);
            *(u16x4*)&hwT[c * 128 + (((node0 >> 3) ^ (c & 7)) << 3) + (node0 & 7)] = hv;
        }
    }
    asm volatile("s_waitcnt lgkmcnt(0)" ::: "memory");
    __builtin_amdgcn_s_barrier();
    __builtin_amdgcn_sched_barrier(0);

    f32x4 acc2[2][3];
    #pragma unroll
    for (int i = 0; i < 2; ++i)
        #pragma unroll
        for (int j = 0; j < 3; ++j)
            acc2[i][j] = (f32x4){0.f, 0.f, 0.f, 0.f};

    #pragma unroll
    for (int ks = 0; ks < 4; ++ks) {
        short8 bf[3];
        #pragma unroll
        for (int f = 0; f < 3; ++f) {
            const int c = wc * 48 + f * 16 + lr;
            bf[f] = *(const short8*)&hwT[c * 128 + (((ks * 4 + lh) ^ (c & 7)) << 3)];
        }
        #pragma unroll
        for (int mf = 0; mf < 2; ++mf)
            #pragma unroll
            for (int nf = 0; nf < 3; ++nf)
                acc2[mf][nf] = __builtin_amdgcn_mfma_f32_16x16x32_f16(adjr[mf * 4 + ks], bf[nf], acc2[mf][nf], 0, 0, 0);
    }

    // epilogue: out = relu(acc2*inv + bias) + X_in; split fp16; store FRAG
    #pragma unroll
    for (int mf = 0; mf < 2; ++mf) {
        const int mblk = mblk0 + mf;
        #pragma unroll
        for (int r = 0; r < 4; ++r) {
            const int node = wr * 32 + mf * 16 + lh * 4 + r;
            const int lane_r = lh * 4 + r;
            const float inv = invden[bmb * N_ + node];
            #pragma unroll
            for (int nf = 0; nf < 3; ++nf) {
                const int c = bn + wc * 48 + nf * 16 + lr;
                const int idx = (mblk * 24 + (c >> 5)) * 512
                              + ((c >> 3) & 3) * 128 + lane_r * 8 + (c & 7);
                float v = fmaxf(acc2[mf][nf][r] * inv + bias[c], 0.f);
                v += h2f(Ah[idx]) + h2f(Al[idx]);   // residual = A-source
                u16 h, l; split2h(v, h, l);
                Oh[idx] = h; Ol[idx] = l;
            }
        }
    }
}

// ---------------------------------------------------------------------------
__global__ __launch_bounds__(192)
void gcn_target_kernel(const u16* __restrict__ Xh, const u16* __restrict__ Xl,
                       const int* __restrict__ gspan, float* __restrict__ gt) {
    const int b = blockIdx.x;
    const int s = gspan[b * 2 + 0];
    const int e = gspan[b * 2 + 1];
    const int d4 = threadIdx.x;
    float4 acc = make_float4(0.f, 0.f, 0.f, 0.f);
    for (int n = s; n < e; ++n) {
        const int idx = fragIdx(b * N_ + n, d4 * 4);
        const u16x4 h = *(const u16x4*)(Xh + idx);
        const u16x4 l = *(const u16x4*)(Xl + idx);
        acc.x += h2f(h[0]) + h2f(l[0]);
        acc.y += h2f(h[1]) + h2f(l[1]);
        acc.z += h2f(h[2]) + h2f(l[2]);
        acc.w += h2f(h[3]) + h2f(l[3]);
    }
    reinterpret_cast<float4*>(gt + (size_t)b * D_)[d4] = acc;
}

// ---------------------------------------------------------------------------
__global__ __launch_bounds__(256)
void head_kernel(const float* __restrict__ tmax, const float* __restrict__ gt,
                 const float* __restrict__ fcW, const float* __restrict__ fcb,
                 float* __restrict__ out) {
    const int b = blockIdx.x;
    const int t = threadIdx.x;
    float p0 = 0.f, p1 = 0.f, p2 = 0.f;
    for (int i = t; i < 2 * D_; i += 256) {
        const float v = (i < D_) ? tmax[(size_t)b * D_ + i] : gt[(size_t)b * D_ + i - D_];
        p0 += v * fcW[i * 3 + 0];
        p1 += v * fcW[i * 3 + 1];
        p2 += v * fcW[i * 3 + 2];
    }
    #pragma unroll
    for (int off = 32; off; off >>= 1) {
        p0 += __shfl_down(p0, off, 64);
        p1 += __shfl_down(p1, off, 64);
        p2 += __shfl_down(p2, off, 64);
    }
    __shared__ float red[4][3];
    const int wv = t >> 6;
    if ((t & 63) == 0) { red[wv][0] = p0; red[wv][1] = p1; red[wv][2] = p2; }
    __syncthreads();
    if (t == 0) {
        #pragma unroll
        for (int o = 0; o < 3; ++o) {
            const float s = red[0][o] + red[1][o] + red[2][o] + red[3][o] + fcb[o];
            out[b * 3 + o] = tanhf(s);
        }
    }
}

// ---------------------------------------------------------------------------
extern "C" void kernel_launch(void* const* d_in, const int* in_sizes, int n_in,
                              void* d_out, int out_size, void* d_ws, size_t ws_size,
                              hipStream_t stream) {
    const float* se   = (const float*)d_in[0];
    const float* dg   = (const float*)d_in[1];
    const float* dg1  = (const float*)d_in[2];
    const float* Wp   = (const float*)d_in[3];
    const float* Wg[3] = {(const float*)d_in[4], (const float*)d_in[6], (const float*)d_in[8]};
    const float* bg[3] = {(const float*)d_in[5], (const float*)d_in[7], (const float*)d_in[9]};
    const float* fcW  = (const float*)d_in[10];
    const float* fcb  = (const float*)d_in[11];
    const int*   tspan  = (const int*)d_in[12];
    const int*   nspans = (const int*)d_in[13];
    const int*   gspan  = (const int*)d_in[14];
    float* out = (float*)d_out;

    // workspace layout (u16 units unless noted)
    u16* us   = (u16*)d_ws;
    u16* X0h  = us;                        // 8192*768 each (FRAG layout)
    u16* X0l  = X0h + 6291456;
    u16* X1h  = X0l + 6291456;
    u16* X1l  = X1h + 6291456;
    u16* TH   = X1l + 6291456;             // tmps hi/lo (FRAG layout)
    u16* TL   = TH  + 6291456;
    u16* WTh  = TL  + 6291456;             // 4*768*768 fp16 (single)
    u16* ADJ  = WTh + 2359296;             // 64*128*128 fp16
    float* INV = (float*)(ADJ + 1048576);  // 8192
    float* TMX = INV + 8192;               // 64*768
    float* GT  = TMX + 49152;              // 64*768

    // Stage A: ragged prep
    span_split_kernel<<<B_ * N_, 192, 0, stream>>>(se, nspans, TH, TL);
    target_max_kernel<<<B_, 192, 0, stream>>>(se, tspan, TMX);
    adj_kernel<<<B_ * N_, 128, 0, stream>>>(dg, dg1, ADJ, INV);
    wsplit_kernel<<<dim3(12, 12, 4), 256, 0, stream>>>(Wp, Wg[0], Wg[1], Wg[2], WTh);

    // Stage B: X0 = relu(tmps @ W_proj)   (512 blocks: 64 row-panels x 8 col-96)
    gemm_fused<0><<<512, 512, 0, stream>>>(TH, TL, WTh,
                                           nullptr, nullptr, nullptr, X0h, X0l);

    // Stage C: 3 fused GCN layers (ping-pong X0 <-> X1)
    const u16* inh[3] = {X0h, X1h, X0h};
    const u16* inl[3] = {X0l, X1l, X0l};
    u16* outh[3] = {X1h, X0h, X1h};
    u16* outl[3] = {X1l, X0l, X1l};
    for (int l = 0; l < 3; ++l) {
        const size_t wo = (size_t)(l + 1) * D_ * D_;
        gemm_fused<1><<<512, 512, 0, stream>>>(inh[l], inl[l], WTh + wo,
                                               ADJ, INV, bg[l], outh[l], outl[l]);
    }

    // Stage D: ragged node-span sum + head (final X lives in X1)
    gcn_target_kernel<<<B_, 192, 0, stream>>>(X1h, X1l, gspan, GT);
    head_kernel<<<B_, 256, 0, stream>>>(TMX, GT, fcW, fcb, out);
}

// Round 11
// 145.499 us; speedup vs baseline: 1.8792x; 1.1671x over previous
//
#include <hip/hip_runtime.h>
#include <float.h>
#include <math.h>

typedef __attribute__((ext_vector_type(8))) short short8;
typedef __attribute__((ext_vector_type(4))) float f32x4;
typedef __attribute__((ext_vector_type(4))) unsigned short u16x4;
typedef unsigned short u16;
typedef unsigned int u32;

constexpr int B_ = 64, S_ = 512, N_ = 128, D_ = 768;

// ---------------------------------------------------------------------------
__device__ inline void split2h(float x, u16& h, u16& l) {
    _Float16 hh = (_Float16)x;
    _Float16 ll = (_Float16)(x - (float)hh);
    h = __builtin_bit_cast(u16, hh);
    l = __builtin_bit_cast(u16, ll);
}
__device__ inline u16 f2h(float x) {
    _Float16 hh = (_Float16)x;
    return __builtin_bit_cast(u16, hh);
}
__device__ inline float h2f(u16 h) {
    return (float)__builtin_bit_cast(_Float16, h);
}

__device__ inline void gload_lds16(const u16* g, u16* s) {
    __builtin_amdgcn_global_load_lds(
        (const __attribute__((address_space(1))) u32*)g,
        (__attribute__((address_space(3))) u32*)s, 16, 0, 0);
}

// Fragment-major layout for activation matrices [M][768]:
// u16 index of (row, col) = ((row>>4)*24 + (col>>5))*512
//                         + ((col>>3)&3)*128 + (row&15)*8 + (col&7)
__device__ inline int fragIdx(int row, int col) {
    return ((row >> 4) * 24 + (col >> 5)) * 512 + ((col >> 3) & 3) * 128
         + (row & 15) * 8 + (col & 7);
}

// ---------------------------------------------------------------------------
// tmps[b,n,:] = sum_{r=s+1..e} se[b,r,:]  -> split fp16 hi/lo, FRAG layout
__global__ __launch_bounds__(192)
void span_split_kernel(const float* __restrict__ se, const int* __restrict__ spans,
                       u16* __restrict__ th, u16* __restrict__ tl) {
    const int bn = blockIdx.x;
    const int b  = bn >> 7;
    const int s  = spans[bn * 2 + 0];
    const int e  = spans[bn * 2 + 1];
    const float* base = se + (size_t)b * S_ * D_;
    const int d4 = threadIdx.x;
    float4 acc = make_float4(0.f, 0.f, 0.f, 0.f);
    for (int r = s + 1; r <= e; ++r) {
        const float4 v = reinterpret_cast<const float4*>(base + (size_t)r * D_)[d4];
        acc.x += v.x; acc.y += v.y; acc.z += v.z; acc.w += v.w;
    }
    u16x4 hv, lv;
    u16 hh, ll;
    split2h(acc.x, hh, ll); hv[0] = hh; lv[0] = ll;
    split2h(acc.y, hh, ll); hv[1] = hh; lv[1] = ll;
    split2h(acc.z, hh, ll); hv[2] = hh; lv[2] = ll;
    split2h(acc.w, hh, ll); hv[3] = hh; lv[3] = ll;
    const int idx = fragIdx(bn, d4 * 4);
    *(u16x4*)(th + idx) = hv;
    *(u16x4*)(tl + idx) = lv;
}

// ---------------------------------------------------------------------------
__global__ __launch_bounds__(192)
void target_max_kernel(const float* __restrict__ se, const int* __restrict__ tspan,
                       float* __restrict__ tmax) {
    const int b = blockIdx.x;
    const int s = tspan[b * 2 + 0];
    const int e = tspan[b * 2 + 1];
    const float* base = se + (size_t)b * S_ * D_;
    const int d4 = threadIdx.x;
    float4 m = make_float4(-FLT_MAX, -FLT_MAX, -FLT_MAX, -FLT_MAX);
    for (int r = s; r < e; ++r) {
        const float4 v = reinterpret_cast<const float4*>(base + (size_t)r * D_)[d4];
        m.x = fmaxf(m.x, v.x); m.y = fmaxf(m.y, v.y);
        m.z = fmaxf(m.z, v.z); m.w = fmaxf(m.w, v.w);
    }
    reinterpret_cast<float4*>(tmax + (size_t)b * D_)[d4] = m;
}

// ---------------------------------------------------------------------------
// adj = clamp(dg+dg1,1) -> fp16 (exact {0,1}) [b][n][k]; invden = 1/(rowsum+1e-7)
__global__ __launch_bounds__(128)
void adj_kernel(const float* __restrict__ dg, const float* __restrict__ dg1,
                u16* __restrict__ adj, float* __restrict__ invden) {
    const int row = blockIdx.x;
    const int t   = threadIdx.x;
    const size_t idx = (size_t)row * N_ + t;
    float a = dg[idx] + dg1[idx];
    a = (a >= 1.f) ? 1.f : a;
    adj[idx] = f2h(a);
    float w = a;
    #pragma unroll
    for (int off = 32; off; off >>= 1) w += __shfl_down(w, off, 64);
    __shared__ float ssum[2];
    if ((t & 63) == 0) ssum[t >> 6] = w;
    __syncthreads();
    if (t == 0) invden[row] = 1.f / (ssum[0] + ssum[1] + 1e-7f);
}

// ---------------------------------------------------------------------------
// Weights: W[k][n] (768x768) -> WT[n][k] single fp16. blockIdx.z = matrix.
__global__ __launch_bounds__(256)
void wsplit_kernel(const float* __restrict__ W0, const float* __restrict__ W1,
                   const float* __restrict__ W2, const float* __restrict__ W3,
                   u16* __restrict__ wth) {
    __shared__ float t[64][65];
    const int mi = blockIdx.z;
    const float* W = (mi == 0) ? W0 : (mi == 1) ? W1 : (mi == 2) ? W2 : W3;
    const int k0 = blockIdx.y * 64, n0 = blockIdx.x * 64;
    #pragma unroll 4
    for (int it = 0; it < 16; ++it) {
        const int lin = it * 256 + threadIdx.x;
        const int r = lin >> 6, c = lin & 63;
        t[r][c] = W[(size_t)(k0 + r) * D_ + n0 + c];
    }
    __syncthreads();
    u16* oh = wth + (size_t)mi * D_ * D_;
    #pragma unroll 4
    for (int it = 0; it < 16; ++it) {
        const int lin = it * 256 + threadIdx.x;
        const int r = lin >> 6, c = lin & 63;
        oh[(size_t)(n0 + r) * D_ + k0 + c] = f2h(t[c][r]);
    }
}

// ---------------------------------------------------------------------------
// Fused fp16 GEMM, SINGLE-A-operand (H ~= Ah @ W; hi/lo kept in storage only).
// 128x96 tile, 8 waves (4x2), 512 blocks (2/CU, 16 waves/CU).
// Single-barrier K-loop: A regs triple-buffered (2 iters ahead), B LDS
// tri-buffered (3 x 6 KB, staged after the barrier into the buffer freed
// 2 iters ago). Counted vmcnt (steady 5/4), no mid-loop drains.
// MODE 0: store relu(H) split fp16 hi/lo, FRAG layout.
// MODE 1: out = relu((adj[b]@H)*invden + bias) + X_in (FRAG layout);
//   adj in VGPRs post-loop; hwT (24 KB) reuses LDS after a drain barrier.
template<int MODE>
__global__ __launch_bounds__(512, 4)
void gemm_fused(const u16* __restrict__ Ah, const u16* __restrict__ Al,
                const u16* __restrict__ Bh,
                const u16* __restrict__ ADJ, const float* __restrict__ invden,
                const float* __restrict__ bias,
                u16* __restrict__ Oh, u16* __restrict__ Ol) {
    __shared__ u16 lds[12288];   // 24 KB: B tri-buf [0,9216); hwT uses [0,12288)
    const int tid  = threadIdx.x;
    const int lane = tid & 63, w = tid >> 6;     // 8 waves
    const int wr = w >> 1, wc = w & 1;           // 4 row x 2 col
    const int lr = lane & 15, lh = lane >> 4;

    int bid = blockIdx.x;
    bid = (bid & 7) * 64 + (bid >> 3);           // XCD swizzle (512 % 8 == 0)
    const int bnb = bid & 7, bmb = bid >> 3;
    const int bn = bnb * 96;

    // --- B staging: wave w<6 stages one 1KB group per tile ---
    const int qch = (lane & 3) ^ ((lane >> 3) & 3);
    const u16* gBsrc = Bh + (size_t)(bn + w * 16 + (lane >> 2)) * 768 + qch * 8;

    // --- A frag bases: wave owns mblks mblk0, mblk0+1 (hi stream only) ---
    const int mblk0 = bmb * 8 + wr * 2;
    const u16* gAh = Ah + (size_t)mblk0 * 12288 + lane * 8;

    f32x4 acc[2][3];
    #pragma unroll
    for (int i = 0; i < 2; ++i)
        #pragma unroll
        for (int j = 0; j < 3; ++j)
            acc[i][j] = (f32x4){0.f, 0.f, 0.f, 0.f};

    short8 aS0[2], aS1[2], aS2[2];   // 3 A-sets (hi frags for mblk0, mblk0+1)

    // prologue (issue order matters for vmcnt counting): A0, B0, B1, A1
    #pragma unroll
    for (int mf = 0; mf < 2; ++mf)
        asm volatile("global_load_dwordx4 %0, %1, off"
                     : "=v"(aS0[mf]) : "v"(gAh + mf * 12288) : "memory");
    if (w < 6) {
        gload_lds16(gBsrc, lds + w * 512);                 // B0 -> buf0
        gload_lds16(gBsrc + 32, lds + 3072 + w * 512);     // B1 -> buf1
    }
    #pragma unroll
    for (int mf = 0; mf < 2; ++mf)
        asm volatile("global_load_dwordx4 %0, %1, off"
                     : "=v"(aS1[mf]) : "v"(gAh + mf * 12288 + 512) : "memory");

    const int pB = (lh ^ ((lr >> 1) & 3)) << 3;  // B frag phys chunk offset (u16)

// One K-step. C = compile-time phase (t_ % 3); CUR = A-set for tile t_;
// N2 = A-set receiving tile t_+2. Single barrier; stage after barrier.
#define GEMM_ITER(C, CUR, N2)                                                 \
    {                                                                         \
        const int t_ = 3 * tt + (C);                                          \
        if (t_ <= 21) {                                                       \
            _Pragma("unroll")                                                 \
            for (int mf = 0; mf < 2; ++mf)                                    \
                asm volatile("global_load_dwordx4 %0, %1, off"                \
                    : "=v"(N2[mf])                                            \
                    : "v"(gAh + mf * 12288 + (t_ + 2) * 512) : "memory");     \
            if (w < 6) asm volatile("s_waitcnt vmcnt(5)" ::: "memory");       \
            else       asm volatile("s_waitcnt vmcnt(4)" ::: "memory");       \
        } else if (t_ == 22) {                                                \
            if (w < 6) asm volatile("s_waitcnt vmcnt(3)" ::: "memory");       \
            else       asm volatile("s_waitcnt vmcnt(2)" ::: "memory");       \
        } else {                                                              \
            asm volatile("s_waitcnt vmcnt(0)" ::: "memory");                  \
        }                                                                     \
        __builtin_amdgcn_s_barrier();                                         \
        __builtin_amdgcn_sched_barrier(0);                                    \
        if (t_ <= 21 && w < 6)                                                \
            gload_lds16(gBsrc + (t_ + 2) * 32,                                \
                        lds + (((C) + 2) % 3) * 3072 + w * 512);              \
        const u16* Lb = lds + ((C) % 3) * 3072;                               \
        short8 bh4[3];                                                        \
        _Pragma("unroll")                                                     \
        for (int f = 0; f < 3; ++f)                                           \
            bh4[f] = *(const short8*)&Lb[(wc * 48 + f * 16 + lr) * 32 + pB];  \
        __builtin_amdgcn_s_setprio(1);                                        \
        _Pragma("unroll")                                                     \
        for (int mf = 0; mf < 2; ++mf)                                        \
            _Pragma("unroll")                                                 \
            for (int nf = 0; nf < 3; ++nf)                                    \
                acc[mf][nf] = __builtin_amdgcn_mfma_f32_16x16x32_f16(CUR[mf], bh4[nf], acc[mf][nf], 0, 0, 0); \
        __builtin_amdgcn_s_setprio(0);                                        \
    }

    for (int tt = 0; tt < 8; ++tt) {
        GEMM_ITER(0, aS0, aS2)
        GEMM_ITER(1, aS1, aS0)
        GEMM_ITER(2, aS2, aS1)
    }
#undef GEMM_ITER

    if (MODE == 0) {
        #pragma unroll
        for (int mf = 0; mf < 2; ++mf) {
            const int mblk = mblk0 + mf;
            #pragma unroll
            for (int r = 0; r < 4; ++r) {
                const int lane_r = lh * 4 + r;
                #pragma unroll
                for (int nf = 0; nf < 3; ++nf) {
                    const int c = bn + wc * 48 + nf * 16 + lr;
                    const int idx = (mblk * 24 + (c >> 5)) * 512
                                  + ((c >> 3) & 3) * 128 + lane_r * 8 + (c & 7);
                    const float v = fmaxf(acc[mf][nf][r], 0.f);
                    u16 h, l; split2h(v, h, l);
                    Oh[idx] = h; Ol[idx] = l;
                }
            }
        }
        return;
    }

    // ---------------- MODE 1: phase 2 (adjacency GEMM) ----------------------
    // drain: all waves done reading buf2 before hwT overwrites LDS
    __builtin_amdgcn_s_barrier();
    __builtin_amdgcn_sched_barrier(0);

    // adj fragments straight to VGPRs (once per block)
    const u16* adjb = ADJ + (size_t)bmb * (N_ * N_);
    short8 adjr[8];
    #pragma unroll
    for (int mf = 0; mf < 2; ++mf)
        #pragma unroll
        for (int ks = 0; ks < 4; ++ks)
            adjr[mf * 4 + ks] = *(const short8*)(adjb +
                (size_t)(wr * 32 + mf * 16 + lr) * 128 + ks * 32 + lh * 8);

    // write H^T (single fp16) into LDS [c 96][node 128], chunk-swizzled
    u16* hwT = lds;
    #pragma unroll
    for (int mf = 0; mf < 2; ++mf) {
        const int node0 = wr * 32 + mf * 16 + lh * 4;
        #pragma unroll
        for (int nf = 0; nf < 3; ++nf) {
            const int c = wc * 48 + nf * 16 + lr;
            u16x4 hv;
            #pragma unroll
            for (int r = 0; r < 4; ++r) hv[r] = f2h(acc[mf][nf][r]);
            *(u16x4*)&hwT[c * 128 + (((node0 >> 3) ^ (c & 7)) << 3) + (node0 & 7)] = hv;
        }
    }
    asm volatile("s_waitcnt lgkmcnt(0)" ::: "memory");
    __builtin_amdgcn_s_barrier();
    __builtin_amdgcn_sched_barrier(0);

    f32x4 acc2[2][3];
    #pragma unroll
    for (int i = 0; i < 2; ++i)
        #pragma unroll
        for (int j = 0; j < 3; ++j)
            acc2[i][j] = (f32x4){0.f, 0.f, 0.f, 0.f};

    #pragma unroll
    for (int ks = 0; ks < 4; ++ks) {
        short8 bf[3];
        #pragma unroll
        for (int f = 0; f < 3; ++f) {
            const int c = wc * 48 + f * 16 + lr;
            bf[f] = *(const short8*)&hwT[c * 128 + (((ks * 4 + lh) ^ (c & 7)) << 3)];
        }
        #pragma unroll
        for (int mf = 0; mf < 2; ++mf)
            #pragma unroll
            for (int nf = 0; nf < 3; ++nf)
                acc2[mf][nf] = __builtin_amdgcn_mfma_f32_16x16x32_f16(adjr[mf * 4 + ks], bf[nf], acc2[mf][nf], 0, 0, 0);
    }

    // epilogue: out = relu(acc2*inv + bias) + X_in; split fp16; store FRAG
    #pragma unroll
    for (int mf = 0; mf < 2; ++mf) {
        const int mblk = mblk0 + mf;
        #pragma unroll
        for (int r = 0; r < 4; ++r) {
            const int node = wr * 32 + mf * 16 + lh * 4 + r;
            const int lane_r = lh * 4 + r;
            const float inv = invden[bmb * N_ + node];
            #pragma unroll
            for (int nf = 0; nf < 3; ++nf) {
                const int c = bn + wc * 48 + nf * 16 + lr;
                const int idx = (mblk * 24 + (c >> 5)) * 512
                              + ((c >> 3) & 3) * 128 + lane_r * 8 + (c & 7);
                float v = fmaxf(acc2[mf][nf][r] * inv + bias[c], 0.f);
                v += h2f(Ah[idx]) + h2f(Al[idx]);   // residual = A-source hi+lo
                u16 h, l; split2h(v, h, l);
                Oh[idx] = h; Ol[idx] = l;
            }
        }
    }
}

// ---------------------------------------------------------------------------
__global__ __launch_bounds__(192)
void gcn_target_kernel(const u16* __restrict__ Xh, const u16* __restrict__ Xl,
                       const int* __restrict__ gspan, float* __restrict__ gt) {
    const int b = blockIdx.x;
    const int s = gspan[b * 2 + 0];
    const int e = gspan[b * 2 + 1];
    const int d4 = threadIdx.x;
    float4 acc = make_float4(0.f, 0.f, 0.f, 0.f);
    for (int n = s; n < e; ++n) {
        const int idx = fragIdx(b * N_ + n, d4 * 4);
        const u16x4 h = *(const u16x4*)(Xh + idx);
        const u16x4 l = *(const u16x4*)(Xl + idx);
        acc.x += h2f(h[0]) + h2f(l[0]);
        acc.y += h2f(h[1]) + h2f(l[1]);
        acc.z += h2f(h[2]) + h2f(l[2]);
        acc.w += h2f(h[3]) + h2f(l[3]);
    }
    reinterpret_cast<float4*>(gt + (size_t)b * D_)[d4] = acc;
}

// ---------------------------------------------------------------------------
__global__ __launch_bounds__(256)
void head_kernel(const float* __restrict__ tmax, const float* __restrict__ gt,
                 const float* __restrict__ fcW, const float* __restrict__ fcb,
                 float* __restrict__ out) {
    const int b = blockIdx.x;
    const int t = threadIdx.x;
    float p0 = 0.f, p1 = 0.f, p2 = 0.f;
    for (int i = t; i < 2 * D_; i += 256) {
        const float v = (i < D_) ? tmax[(size_t)b * D_ + i] : gt[(size_t)b * D_ + i - D_];
        p0 += v * fcW[i * 3 + 0];
        p1 += v * fcW[i * 3 + 1];
        p2 += v * fcW[i * 3 + 2];
    }
    #pragma unroll
    for (int off = 32; off; off >>= 1) {
        p0 += __shfl_down(p0, off, 64);
        p1 += __shfl_down(p1, off, 64);
        p2 += __shfl_down(p2, off, 64);
    }
    __shared__ float red[4][3];
    const int wv = t >> 6;
    if ((t & 63) == 0) { red[wv][0] = p0; red[wv][1] = p1; red[wv][2] = p2; }
    __syncthreads();
    if (t == 0) {
        #pragma unroll
        for (int o = 0; o < 3; ++o) {
            const float s = red[0][o] + red[1][o] + red[2][o] + red[3][o] + fcb[o];
            out[b * 3 + o] = tanhf(s);
        }
    }
}

// ---------------------------------------------------------------------------
extern "C" void kernel_launch(void* const* d_in, const int* in_sizes, int n_in,
                              void* d_out, int out_size, void* d_ws, size_t ws_size,
                              hipStream_t stream) {
    const float* se   = (const float*)d_in[0];
    const float* dg   = (const float*)d_in[1];
    const float* dg1  = (const float*)d_in[2];
    const float* Wp   = (const float*)d_in[3];
    const float* Wg[3] = {(const float*)d_in[4], (const float*)d_in[6], (const float*)d_in[8]};
    const float* bg[3] = {(const float*)d_in[5], (const float*)d_in[7], (const float*)d_in[9]};
    const float* fcW  = (const float*)d_in[10];
    const float* fcb  = (const float*)d_in[11];
    const int*   tspan  = (const int*)d_in[12];
    const int*   nspans = (const int*)d_in[13];
    const int*   gspan  = (const int*)d_in[14];
    float* out = (float*)d_out;

    // workspace layout (u16 units unless noted)
    u16* us   = (u16*)d_ws;
    u16* X0h  = us;                        // 8192*768 each (FRAG layout)
    u16* X0l  = X0h + 6291456;
    u16* X1h  = X0l + 6291456;
    u16* X1l  = X1h + 6291456;
    u16* TH   = X1l + 6291456;             // tmps hi/lo (FRAG layout)
    u16* TL   = TH  + 6291456;
    u16* WTh  = TL  + 6291456;             // 4*768*768 fp16 (single)
    u16* ADJ  = WTh + 2359296;             // 64*128*128 fp16
    float* INV = (float*)(ADJ + 1048576);  // 8192
    float* TMX = INV + 8192;               // 64*768
    float* GT  = TMX + 49152;              // 64*768

    // Stage A: ragged prep
    span_split_kernel<<<B_ * N_, 192, 0, stream>>>(se, nspans, TH, TL);
    target_max_kernel<<<B_, 192, 0, stream>>>(se, tspan, TMX);
    adj_kernel<<<B_ * N_, 128, 0, stream>>>(dg, dg1, ADJ, INV);
    wsplit_kernel<<<dim3(12, 12, 4), 256, 0, stream>>>(Wp, Wg[0], Wg[1], Wg[2], WTh);

    // Stage B: X0 = relu(tmps @ W_proj)   (512 blocks: 64 row-panels x 8 col-96)
    gemm_fused<0><<<512, 512, 0, stream>>>(TH, TL, WTh,
                                           nullptr, nullptr, nullptr, X0h, X0l);

    // Stage C: 3 fused GCN layers (ping-pong X0 <-> X1)
    const u16* inh[3] = {X0h, X1h, X0h};
    const u16* inl[3] = {X0l, X1l, X0l};
    u16* outh[3] = {X1h, X0h, X1h};
    u16* outl[3] = {X1l, X0l, X1l};
    for (int l = 0; l < 3; ++l) {
        const size_t wo = (size_t)(l + 1) * D_ * D_;
        gemm_fused<1><<<512, 512, 0, stream>>>(inh[l], inl[l], WTh + wo,
                                               ADJ, INV, bg[l], outh[l], outl[l]);
    }

    // Stage D: ragged node-span sum + head (final X lives in X1)
    gcn_target_kernel<<<B_, 192, 0, stream>>>(X1h, X1l, gspan, GT);
    head_kernel<<<B_, 256, 0, stream>>>(TMX, GT, fcW, fcb, out);
}

// Round 12
// 136.103 us; speedup vs baseline: 2.0090x; 1.0690x over previous
//
#include <hip/hip_runtime.h>
#include <float.h>
#include <math.h>

typedef __attribute__((ext_vector_type(8))) short short8;
typedef __attribute__((ext_vector_type(4))) float f32x4;
typedef __attribute__((ext_vector_type(4))) unsigned short u16x4;
typedef unsigned short u16;
typedef unsigned int u32;

constexpr int B_ = 64, S_ = 512, N_ = 128, D_ = 768;

// ---------------------------------------------------------------------------
__device__ inline void split2h(float x, u16& h, u16& l) {
    _Float16 hh = (_Float16)x;
    _Float16 ll = (_Float16)(x - (float)hh);
    h = __builtin_bit_cast(u16, hh);
    l = __builtin_bit_cast(u16, ll);
}
__device__ inline u16 f2h(float x) {
    _Float16 hh = (_Float16)x;
    return __builtin_bit_cast(u16, hh);
}
__device__ inline float h2f(u16 h) {
    return (float)__builtin_bit_cast(_Float16, h);
}

__device__ inline void gload_lds16(const u16* g, u16* s) {
    __builtin_amdgcn_global_load_lds(
        (const __attribute__((address_space(1))) u32*)g,
        (__attribute__((address_space(3))) u32*)s, 16, 0, 0);
}

// Fragment-major layout for activation matrices [M][768]:
// u16 index of (row, col) = ((row>>4)*24 + (col>>5))*512
//                         + ((col>>3)&3)*128 + (row&15)*8 + (col&7)
__device__ inline int fragIdx(int row, int col) {
    return ((row >> 4) * 24 + (col >> 5)) * 512 + ((col >> 3) & 3) * 128
         + (row & 15) * 8 + (col & 7);
}

// ---------------------------------------------------------------------------
// tmps[b,n,:] = sum_{r=s+1..e} se[b,r,:]  -> split fp16 hi/lo, FRAG layout
__global__ __launch_bounds__(192)
void span_split_kernel(const float* __restrict__ se, const int* __restrict__ spans,
                       u16* __restrict__ th, u16* __restrict__ tl) {
    const int bn = blockIdx.x;
    const int b  = bn >> 7;
    const int s  = spans[bn * 2 + 0];
    const int e  = spans[bn * 2 + 1];
    const float* base = se + (size_t)b * S_ * D_;
    const int d4 = threadIdx.x;
    float4 acc = make_float4(0.f, 0.f, 0.f, 0.f);
    for (int r = s + 1; r <= e; ++r) {
        const float4 v = reinterpret_cast<const float4*>(base + (size_t)r * D_)[d4];
        acc.x += v.x; acc.y += v.y; acc.z += v.z; acc.w += v.w;
    }
    u16x4 hv, lv;
    u16 hh, ll;
    split2h(acc.x, hh, ll); hv[0] = hh; lv[0] = ll;
    split2h(acc.y, hh, ll); hv[1] = hh; lv[1] = ll;
    split2h(acc.z, hh, ll); hv[2] = hh; lv[2] = ll;
    split2h(acc.w, hh, ll); hv[3] = hh; lv[3] = ll;
    const int idx = fragIdx(bn, d4 * 4);
    *(u16x4*)(th + idx) = hv;
    *(u16x4*)(tl + idx) = lv;
}

// ---------------------------------------------------------------------------
// target_max: grid (64, 4); block covers 192 cols of batch b.
__global__ __launch_bounds__(192)
void target_max_kernel(const float* __restrict__ se, const int* __restrict__ tspan,
                       float* __restrict__ tmax) {
    const int b = blockIdx.x;
    const int c = blockIdx.y * 192 + threadIdx.x;
    const int s = tspan[b * 2 + 0];
    const int e = tspan[b * 2 + 1];
    const float* base = se + (size_t)b * S_ * D_ + c;
    float m = -FLT_MAX;
    for (int r = s; r < e; ++r) m = fmaxf(m, base[(size_t)r * D_]);
    tmax[(size_t)b * D_ + c] = m;
}

// ---------------------------------------------------------------------------
// adj = clamp(dg+dg1,1) -> fp16 (exact {0,1}) [b][n][k]; invden = 1/(rowsum+1e-7)
__global__ __launch_bounds__(128)
void adj_kernel(const float* __restrict__ dg, const float* __restrict__ dg1,
                u16* __restrict__ adj, float* __restrict__ invden) {
    const int row = blockIdx.x;
    const int t   = threadIdx.x;
    const size_t idx = (size_t)row * N_ + t;
    float a = dg[idx] + dg1[idx];
    a = (a >= 1.f) ? 1.f : a;
    adj[idx] = f2h(a);
    float w = a;
    #pragma unroll
    for (int off = 32; off; off >>= 1) w += __shfl_down(w, off, 64);
    __shared__ float ssum[2];
    if ((t & 63) == 0) ssum[t >> 6] = w;
    __syncthreads();
    if (t == 0) invden[row] = 1.f / (ssum[0] + ssum[1] + 1e-7f);
}

// ---------------------------------------------------------------------------
// Weights: W[k][n] (768x768) -> WT[n][k] single fp16. blockIdx.z = matrix.
__global__ __launch_bounds__(256)
void wsplit_kernel(const float* __restrict__ W0, const float* __restrict__ W1,
                   const float* __restrict__ W2, const float* __restrict__ W3,
                   u16* __restrict__ wth) {
    __shared__ float t[64][65];
    const int mi = blockIdx.z;
    const float* W = (mi == 0) ? W0 : (mi == 1) ? W1 : (mi == 2) ? W2 : W3;
    const int k0 = blockIdx.y * 64, n0 = blockIdx.x * 64;
    #pragma unroll 4
    for (int it = 0; it < 16; ++it) {
        const int lin = it * 256 + threadIdx.x;
        const int r = lin >> 6, c = lin & 63;
        t[r][c] = W[(size_t)(k0 + r) * D_ + n0 + c];
    }
    __syncthreads();
    u16* oh = wth + (size_t)mi * D_ * D_;
    #pragma unroll 4
    for (int it = 0; it < 16; ++it) {
        const int lin = it * 256 + threadIdx.x;
        const int r = lin >> 6, c = lin & 63;
        oh[(size_t)(n0 + r) * D_ + k0 + c] = f2h(t[c][r]);
    }
}

// ---------------------------------------------------------------------------
// Fused fp16 GEMM (H ~= Ah @ W; hi/lo kept in storage only).
// 128x96 tile, 8 waves (4x2), 512 blocks (2/CU, 16 waves/CU).
// A now staged through LDS ONCE per block (dedup across the wc wave-pair):
// FRAG-major global makes each mblk K-slice a contiguous 1KB -> one
// global_load_lds per wave per iter. A tri-buf 3x8KB, B tri-buf 3x6KB.
// Single barrier per K-step; counted vmcnt (steady 2/1, final 0).
// MODE 0: store relu(H) split fp16 hi/lo, FRAG layout.
// MODE 1: out = relu((adj[b]@H)*invden + bias) + X_in (FRAG layout);
//   adj in VGPRs post-loop; hwT (24 KB) reuses the A region after a drain.
template<int MODE>
__global__ __launch_bounds__(512, 4)
void gemm_fused(const u16* __restrict__ Ah, const u16* __restrict__ Al,
                const u16* __restrict__ Bh,
                const u16* __restrict__ ADJ, const float* __restrict__ invden,
                const float* __restrict__ bias,
                u16* __restrict__ Oh, u16* __restrict__ Ol) {
    __shared__ u16 lds[21504];   // A tri-buf [0,12288) | B tri-buf [12288,21504)
    const int tid  = threadIdx.x;
    const int lane = tid & 63, w = tid >> 6;     // 8 waves
    const int wr = w >> 1, wc = w & 1;           // 4 row x 2 col
    const int lr = lane & 15, lh = lane >> 4;

    int bid = blockIdx.x;
    bid = (bid & 7) * 64 + (bid >> 3);           // XCD swizzle (512 % 8 == 0)
    const int bnb = bid & 7, bmb = bid >> 3;
    const int bn = bnb * 96;

    // --- B staging: wave w<6 stages one 1KB group per tile ---
    const int qch = (lane & 3) ^ ((lane >> 3) & 3);
    const u16* gBsrc = Bh + (size_t)(bn + w * 16 + (lane >> 2)) * 768 + qch * 8;

    // --- A staging: wave w stages mblk (bmb*8 + w); contiguous 1KB per tile ---
    const int mblk0 = bmb * 8 + wr * 2;          // wave's compute mblks
    const u16* gAstage = Ah + (size_t)(bmb * 8 + w) * 12288 + lane * 8;

    f32x4 acc[2][3];
    #pragma unroll
    for (int i = 0; i < 2; ++i)
        #pragma unroll
        for (int j = 0; j < 3; ++j)
            acc[i][j] = (f32x4){0.f, 0.f, 0.f, 0.f};

    // prologue: A0, B0, A1, B1
    gload_lds16(gAstage, lds + w * 512);
    if (w < 6) gload_lds16(gBsrc, lds + 12288 + w * 512);
    gload_lds16(gAstage + 512, lds + 4096 + w * 512);
    if (w < 6) gload_lds16(gBsrc + 32, lds + 12288 + 3072 + w * 512);

    const int pB = (lh ^ ((lr >> 1) & 3)) << 3;  // B frag phys chunk offset (u16)
    const int aOff0 = (wr * 2) * 512 + lane * 8; // A frag offsets in buf
    const int aOff1 = (wr * 2 + 1) * 512 + lane * 8;

// One K-step. C = compile-time phase (t_ % 3). Single barrier; stage after.
#define GEMM_ITER(C)                                                          \
    {                                                                         \
        const int t_ = 3 * tt + (C);                                          \
        if (t_ <= 22) {                                                       \
            if (w < 6) asm volatile("s_waitcnt vmcnt(2)" ::: "memory");       \
            else       asm volatile("s_waitcnt vmcnt(1)" ::: "memory");       \
        } else {                                                              \
            asm volatile("s_waitcnt vmcnt(0)" ::: "memory");                  \
        }                                                                     \
        __builtin_amdgcn_s_barrier();                                         \
        __builtin_amdgcn_sched_barrier(0);                                    \
        if (t_ <= 21) {                                                       \
            gload_lds16(gAstage + (t_ + 2) * 512,                             \
                        lds + (((C) + 2) % 3) * 4096 + w * 512);              \
            if (w < 6)                                                        \
                gload_lds16(gBsrc + (t_ + 2) * 32,                            \
                            lds + 12288 + (((C) + 2) % 3) * 3072 + w * 512);  \
        }                                                                     \
        const u16* La = lds + ((C) % 3) * 4096;                               \
        const u16* Lb = lds + 12288 + ((C) % 3) * 3072;                       \
        short8 aF[2], bF[3];                                                  \
        aF[0] = *(const short8*)&La[aOff0];                                   \
        aF[1] = *(const short8*)&La[aOff1];                                   \
        _Pragma("unroll")                                                     \
        for (int f = 0; f < 3; ++f)                                           \
            bF[f] = *(const short8*)&Lb[(wc * 48 + f * 16 + lr) * 32 + pB];   \
        __builtin_amdgcn_s_setprio(1);                                        \
        _Pragma("unroll")                                                     \
        for (int mf = 0; mf < 2; ++mf)                                        \
            _Pragma("unroll")                                                 \
            for (int nf = 0; nf < 3; ++nf)                                    \
                acc[mf][nf] = __builtin_amdgcn_mfma_f32_16x16x32_f16(aF[mf], bF[nf], acc[mf][nf], 0, 0, 0); \
        __builtin_amdgcn_s_setprio(0);                                        \
    }

    for (int tt = 0; tt < 8; ++tt) {
        GEMM_ITER(0)
        GEMM_ITER(1)
        GEMM_ITER(2)
    }
#undef GEMM_ITER

    if (MODE == 0) {
        #pragma unroll
        for (int mf = 0; mf < 2; ++mf) {
            const int mblk = mblk0 + mf;
            #pragma unroll
            for (int r = 0; r < 4; ++r) {
                const int lane_r = lh * 4 + r;
                #pragma unroll
                for (int nf = 0; nf < 3; ++nf) {
                    const int c = bn + wc * 48 + nf * 16 + lr;
                    const int idx = (mblk * 24 + (c >> 5)) * 512
                                  + ((c >> 3) & 3) * 128 + lane_r * 8 + (c & 7);
                    const float v = fmaxf(acc[mf][nf][r], 0.f);
                    u16 h, l; split2h(v, h, l);
                    Oh[idx] = h; Ol[idx] = l;
                }
            }
        }
        return;
    }

    // ---------------- MODE 1: phase 2 (adjacency GEMM) ----------------------
    // drain: all waves done reading the K-loop buffers before hwT overwrites
    __builtin_amdgcn_s_barrier();
    __builtin_amdgcn_sched_barrier(0);

    // adj fragments straight to VGPRs (once per block)
    const u16* adjb = ADJ + (size_t)bmb * (N_ * N_);
    short8 adjr[8];
    #pragma unroll
    for (int mf = 0; mf < 2; ++mf)
        #pragma unroll
        for (int ks = 0; ks < 4; ++ks)
            adjr[mf * 4 + ks] = *(const short8*)(adjb +
                (size_t)(wr * 32 + mf * 16 + lr) * 128 + ks * 32 + lh * 8);

    // write H^T (single fp16) into LDS [c 96][node 128], chunk-swizzled
    u16* hwT = lds;
    #pragma unroll
    for (int mf = 0; mf < 2; ++mf) {
        const int node0 = wr * 32 + mf * 16 + lh * 4;
        #pragma unroll
        for (int nf = 0; nf < 3; ++nf) {
            const int c = wc * 48 + nf * 16 + lr;
            u16x4 hv;
            #pragma unroll
            for (int r = 0; r < 4; ++r) hv[r] = f2h(acc[mf][nf][r]);
            *(u16x4*)&hwT[c * 128 + (((node0 >> 3) ^ (c & 7)) << 3) + (node0 & 7)] = hv;
        }
    }
    asm volatile("s_waitcnt lgkmcnt(0)" ::: "memory");
    __builtin_amdgcn_s_barrier();
    __builtin_amdgcn_sched_barrier(0);

    f32x4 acc2[2][3];
    #pragma unroll
    for (int i = 0; i < 2; ++i)
        #pragma unroll
        for (int j = 0; j < 3; ++j)
            acc2[i][j] = (f32x4){0.f, 0.f, 0.f, 0.f};

    #pragma unroll
    for (int ks = 0; ks < 4; ++ks) {
        short8 bf[3];
        #pragma unroll
        for (int f = 0; f < 3; ++f) {
            const int c = wc * 48 + f * 16 + lr;
            bf[f] = *(const short8*)&hwT[c * 128 + (((ks * 4 + lh) ^ (c & 7)) << 3)];
        }
        #pragma unroll
        for (int mf = 0; mf < 2; ++mf)
            #pragma unroll
            for (int nf = 0; nf < 3; ++nf)
                acc2[mf][nf] = __builtin_amdgcn_mfma_f32_16x16x32_f16(adjr[mf * 4 + ks], bf[nf], acc2[mf][nf], 0, 0, 0);
    }

    // epilogue: out = relu(acc2*inv + bias) + X_in; split fp16; store FRAG
    #pragma unroll
    for (int mf = 0; mf < 2; ++mf) {
        const int mblk = mblk0 + mf;
        #pragma unroll
        for (int r = 0; r < 4; ++r) {
            const int node = wr * 32 + mf * 16 + lh * 4 + r;
            const int lane_r = lh * 4 + r;
            const float inv = invden[bmb * N_ + node];
            #pragma unroll
            for (int nf = 0; nf < 3; ++nf) {
                const int c = bn + wc * 48 + nf * 16 + lr;
                const int idx = (mblk * 24 + (c >> 5)) * 512
                              + ((c >> 3) & 3) * 128 + lane_r * 8 + (c & 7);
                float v = fmaxf(acc2[mf][nf][r] * inv + bias[c], 0.f);
                v += h2f(Ah[idx]) + h2f(Al[idx]);   // residual = A-source hi+lo
                u16 h, l; split2h(v, h, l);
                Oh[idx] = h; Ol[idx] = l;
            }
        }
    }
}

// ---------------------------------------------------------------------------
// gcn_target: grid (64, 4); block covers 192 cols of batch b.
__global__ __launch_bounds__(192)
void gcn_target_kernel(const u16* __restrict__ Xh, const u16* __restrict__ Xl,
                       const int* __restrict__ gspan, float* __restrict__ gt) {
    const int b = blockIdx.x;
    const int c = blockIdx.y * 192 + threadIdx.x;
    const int s = gspan[b * 2 + 0];
    const int e = gspan[b * 2 + 1];
    float acc = 0.f;
    for (int n = s; n < e; ++n) {
        const int idx = fragIdx(b * N_ + n, c);
        acc += h2f(Xh[idx]) + h2f(Xl[idx]);
    }
    gt[(size_t)b * D_ + c] = acc;
}

// ---------------------------------------------------------------------------
__global__ __launch_bounds__(256)
void head_kernel(const float* __restrict__ tmax, const float* __restrict__ gt,
                 const float* __restrict__ fcW, const float* __restrict__ fcb,
                 float* __restrict__ out) {
    const int b = blockIdx.x;
    const int t = threadIdx.x;
    float p0 = 0.f, p1 = 0.f, p2 = 0.f;
    for (int i = t; i < 2 * D_; i += 256) {
        const float v = (i < D_) ? tmax[(size_t)b * D_ + i] : gt[(size_t)b * D_ + i - D_];
        p0 += v * fcW[i * 3 + 0];
        p1 += v * fcW[i * 3 + 1];
        p2 += v * fcW[i * 3 + 2];
    }
    #pragma unroll
    for (int off = 32; off; off >>= 1) {
        p0 += __shfl_down(p0, off, 64);
        p1 += __shfl_down(p1, off, 64);
        p2 += __shfl_down(p2, off, 64);
    }
    __shared__ float red[4][3];
    const int wv = t >> 6;
    if ((t & 63) == 0) { red[wv][0] = p0; red[wv][1] = p1; red[wv][2] = p2; }
    __syncthreads();
    if (t == 0) {
        #pragma unroll
        for (int o = 0; o < 3; ++o) {
            const float s = red[0][o] + red[1][o] + red[2][o] + red[3][o] + fcb[o];
            out[b * 3 + o] = tanhf(s);
        }
    }
}

// ---------------------------------------------------------------------------
extern "C" void kernel_launch(void* const* d_in, const int* in_sizes, int n_in,
                              void* d_out, int out_size, void* d_ws, size_t ws_size,
                              hipStream_t stream) {
    const float* se   = (const float*)d_in[0];
    const float* dg   = (const float*)d_in[1];
    const float* dg1  = (const float*)d_in[2];
    const float* Wp   = (const float*)d_in[3];
    const float* Wg[3] = {(const float*)d_in[4], (const float*)d_in[6], (const float*)d_in[8]};
    const float* bg[3] = {(const float*)d_in[5], (const float*)d_in[7], (const float*)d_in[9]};
    const float* fcW  = (const float*)d_in[10];
    const float* fcb  = (const float*)d_in[11];
    const int*   tspan  = (const int*)d_in[12];
    const int*   nspans = (const int*)d_in[13];
    const int*   gspan  = (const int*)d_in[14];
    float* out = (float*)d_out;

    // workspace layout (u16 units unless noted)
    u16* us   = (u16*)d_ws;
    u16* X0h  = us;                        // 8192*768 each (FRAG layout)
    u16* X0l  = X0h + 6291456;
    u16* X1h  = X0l + 6291456;
    u16* X1l  = X1h + 6291456;
    u16* TH   = X1l + 6291456;             // tmps hi/lo (FRAG layout)
    u16* TL   = TH  + 6291456;
    u16* WTh  = TL  + 6291456;             // 4*768*768 fp16 (single)
    u16* ADJ  = WTh + 2359296;             // 64*128*128 fp16
    float* INV = (float*)(ADJ + 1048576);  // 8192
    float* TMX = INV + 8192;               // 64*768
    float* GT  = TMX + 49152;              // 64*768

    // Stage A: ragged prep
    span_split_kernel<<<B_ * N_, 192, 0, stream>>>(se, nspans, TH, TL);
    target_max_kernel<<<dim3(B_, 4), 192, 0, stream>>>(se, tspan, TMX);
    adj_kernel<<<B_ * N_, 128, 0, stream>>>(dg, dg1, ADJ, INV);
    wsplit_kernel<<<dim3(12, 12, 4), 256, 0, stream>>>(Wp, Wg[0], Wg[1], Wg[2], WTh);

    // Stage B: X0 = relu(tmps @ W_proj)   (512 blocks: 64 row-panels x 8 col-96)
    gemm_fused<0><<<512, 512, 0, stream>>>(TH, TL, WTh,
                                           nullptr, nullptr, nullptr, X0h, X0l);

    // Stage C: 3 fused GCN layers (ping-pong X0 <-> X1)
    const u16* inh[3] = {X0h, X1h, X0h};
    const u16* inl[3] = {X0l, X1l, X0l};
    u16* outh[3] = {X1h, X0h, X1h};
    u16* outl[3] = {X1l, X0l, X1l};
    for (int l = 0; l < 3; ++l) {
        const size_t wo = (size_t)(l + 1) * D_ * D_;
        gemm_fused<1><<<512, 512, 0, stream>>>(inh[l], inl[l], WTh + wo,
                                               ADJ, INV, bg[l], outh[l], outl[l]);
    }

    // Stage D: ragged node-span sum + head (final X lives in X1)
    gcn_target_kernel<<<dim3(B_, 4), 192, 0, stream>>>(X1h, X1l, gspan, GT);
    head_kernel<<<B_, 256, 0, stream>>>(TMX, GT, fcW, fcb, out);
}